// Round 6
// baseline (372.432 us; speedup 1.0000x reference)
//
#include <hip/hip_runtime.h>
#include <math.h>

#define TT 2048
#define S72 72

typedef __bf16 bf16;
typedef __bf16 bf16x8 __attribute__((ext_vector_type(8)));
typedef __bf16 bf16x4v __attribute__((ext_vector_type(4)));
typedef __bf16 bf16x2v __attribute__((ext_vector_type(2)));
typedef float f32x4 __attribute__((ext_vector_type(4)));

__device__ __forceinline__ float wredsum(float v) {
#pragma unroll
  for (int off = 32; off > 0; off >>= 1) v += __shfl_xor(v, off, 64);
  return v;
}
__device__ __forceinline__ float sigmoidf_(float x) { return 1.f / (1.f + __expf(-x)); }

// ---------------- RMSNorm + a/b projections fused ----------------
__global__ __launch_bounds__(256) void k_rmsnorm(const float* __restrict__ h,
    const float* __restrict__ nw, const float* __restrict__ aw,
    const float* __restrict__ bw, const float* __restrict__ dtb,
    const float* __restrict__ alog, bf16* __restrict__ xb,
    float* __restrict__ graw, float* __restrict__ btb) {
  int t = blockIdx.x, tid = threadIdx.x;
  float4 hv = *(const float4*)(h + (size_t)t*1024 + tid*4);
  float ss = hv.x*hv.x + hv.y*hv.y + hv.z*hv.z + hv.w*hv.w;
  __shared__ float red[4];
  __shared__ __align__(16) float xs[1024];
  float wsum = wredsum(ss);
  if ((tid & 63) == 0) red[tid >> 6] = wsum;
  __syncthreads();
  float tot = red[0] + red[1] + red[2] + red[3];
  float rs = rsqrtf(tot * (1.f/1024.f) + 1e-6f);
  float4 w4 = *(const float4*)(nw + tid*4);
  float4 y;
  y.x = hv.x*rs*w4.x; y.y = hv.y*rs*w4.y; y.z = hv.z*rs*w4.z; y.w = hv.w*rs*w4.w;
  *(float4*)(xs + tid*4) = y;
  bf16x4v b; b[0]=(bf16)y.x; b[1]=(bf16)y.y; b[2]=(bf16)y.z; b[3]=(bf16)y.w;
  *(bf16x4v*)(xb + (size_t)t*1024 + tid*4) = b;
  __syncthreads();
  int wave = tid >> 6, lane = tid & 63;
  const float4* x4 = (const float4*)xs;
#pragma unroll
  for (int hi = 0; hi < 4; ++hi) {
    int hh = wave*4 + hi;
    float sa = 0.f, sb = 0.f;
#pragma unroll
    for (int i = 0; i < 4; ++i) {
      float4 xv = x4[i*64 + lane];
      float4 av = *(const float4*)(aw + hh*1024 + i*256 + lane*4);
      float4 bv = *(const float4*)(bw + hh*1024 + i*256 + lane*4);
      sa += xv.x*av.x + xv.y*av.y + xv.z*av.z + xv.w*av.w;
      sb += xv.x*bv.x + xv.y*bv.y + xv.z*bv.z + xv.w*bv.w;
    }
    sa = wredsum(sa); sb = wredsum(sb);
    if (lane == 0) {
      float ap = sa + dtb[hh];
      float sp = (ap > 20.f) ? ap : log1pf(expf(ap));
      graw[t*16 + hh] = -expf(alog[hh]) * sp;
      btb[t*16 + hh] = 1.f / (1.f + expf(-sb));
    }
  }
}

// ---------------- cast weights f32 -> bf16 (6 tensors) ----------------
__global__ void k_castw(const float* __restrict__ qw, const float* __restrict__ kw,
    const float* __restrict__ vw, const float* __restrict__ gw,
    const float* __restrict__ opw, const float* __restrict__ ow,
    bf16* qwb, bf16* kwb, bf16* vwb, bf16* gwb, bf16* opwb, bf16* owb) {
  for (long u = (long)blockIdx.x*256 + threadIdx.x; u < 2359296; u += (long)gridDim.x*256) {
    const float* src; bf16* dst; long l;
    if      (u <  262144) { src=qw;  dst=qwb;  l=u; }
    else if (u <  524288) { src=kw;  dst=kwb;  l=u-262144; }
    else if (u < 1048576) { src=vw;  dst=vwb;  l=u-524288; }
    else if (u < 1572864) { src=gw;  dst=gwb;  l=u-1048576; }
    else if (u < 2097152) { src=opw; dst=opwb; l=u-1572864; }
    else                  { src=ow;  dst=owb;  l=u-2097152; }
    float4 s = *(const float4*)(src + l*4);
    bf16x4v b; b[0]=(bf16)s.x; b[1]=(bf16)s.y; b[2]=(bf16)s.z; b[3]=(bf16)s.w;
    *(bf16x4v*)(dst + l*4) = b;
  }
}

// ---------------- bf16 MFMA GEMM: C[M,N] = A[M,K] * B[N,K]^T ----------------
// Double-buffered LDS: tile k+1 loads issued AFTER the barrier, overlapping tile-k
// compute. XOR-swizzled staging keeps ds_read_b128 at 2-way bank aliasing (free).
template <typename OutT>
__device__ __forceinline__ void gemm_body(const bf16* __restrict__ A,
    const bf16* __restrict__ B, OutT* __restrict__ C, int N, int K, int m0, int n0) {
  __shared__ bf16 As[2][128*32];
  __shared__ bf16 Bs[2][128*32];
  const int tid = threadIdx.x, lane = tid & 63, wave = tid >> 6;
  const int wm = (wave >> 1) * 64, wn = (wave & 1) * 64;
  const int srow = wave*16 + (lane >> 2);
  const int swl = (((lane & 3) ^ ((lane >> 3) & 3))) * 8;
  const int sdst = (lane & 3) * 8;
  const int quad = lane >> 4, l16 = lane & 15;
  const int sw = (l16 >> 1) & 3;
  f32x4 acc[4][4] = {};
  const int nk = K >> 5;
  // stage tile 0 -> buf 0
#pragma unroll
  for (int i = 0; i < 2; ++i) {
    int r = i*64 + srow;
    __builtin_amdgcn_global_load_lds(
      (__attribute__((address_space(1))) void*)(A + (size_t)(m0 + r)*K + swl),
      (__attribute__((address_space(3))) void*)(&As[0][r*32 + sdst]), 16, 0, 0);
    __builtin_amdgcn_global_load_lds(
      (__attribute__((address_space(1))) void*)(B + (size_t)(n0 + r)*K + swl),
      (__attribute__((address_space(3))) void*)(&Bs[0][r*32 + sdst]), 16, 0, 0);
  }
  for (int kt = 0; kt < nk; ++kt) {
    const int cur = kt & 1;
    __syncthreads();
    bf16x8 af[4], bfr[4];
#pragma unroll
    for (int mt = 0; mt < 4; ++mt)
      af[mt] = *(const bf16x8*)(&As[cur][(wm + mt*16 + l16)*32 + (quad ^ sw)*8]);
#pragma unroll
    for (int nt = 0; nt < 4; ++nt)
      bfr[nt] = *(const bf16x8*)(&Bs[cur][(wn + nt*16 + l16)*32 + (quad ^ sw)*8]);
    if (kt + 1 < nk) {
      int k0 = (kt + 1) << 5;
#pragma unroll
      for (int i = 0; i < 2; ++i) {
        int r = i*64 + srow;
        __builtin_amdgcn_global_load_lds(
          (__attribute__((address_space(1))) void*)(A + (size_t)(m0 + r)*K + k0 + swl),
          (__attribute__((address_space(3))) void*)(&As[cur^1][r*32 + sdst]), 16, 0, 0);
        __builtin_amdgcn_global_load_lds(
          (__attribute__((address_space(1))) void*)(B + (size_t)(n0 + r)*K + k0 + swl),
          (__attribute__((address_space(3))) void*)(&Bs[cur^1][r*32 + sdst]), 16, 0, 0);
      }
    }
#pragma unroll
    for (int mt = 0; mt < 4; ++mt)
#pragma unroll
      for (int nt = 0; nt < 4; ++nt)
        acc[mt][nt] = __builtin_amdgcn_mfma_f32_16x16x32_bf16(af[mt], bfr[nt], acc[mt][nt], 0, 0, 0);
  }
#pragma unroll
  for (int mt = 0; mt < 4; ++mt)
#pragma unroll
    for (int nt = 0; nt < 4; ++nt)
#pragma unroll
      for (int r = 0; r < 4; ++r) {
        int row = m0 + wm + mt*16 + quad*4 + r;
        int col = n0 + wn + nt*16 + l16;
        C[(size_t)row*N + col] = (OutT)acc[mt][nt][r];
      }
}

// proj GEMM: flattened grid (48 x-tiles), bf16 outputs
__global__ __launch_bounds__(256) void k_gemm_proj(const bf16* __restrict__ A,
    const bf16* __restrict__ qwb, const bf16* __restrict__ kwb,
    const bf16* __restrict__ vwb, const bf16* __restrict__ gwb,
    bf16* __restrict__ qpre, bf16* __restrict__ kpre,
    bf16* __restrict__ vpre, bf16* __restrict__ gpre) {
  int bx = blockIdx.x;
  const bf16* B; bf16* C; int N, xt;
  if      (bx <  8) { B = qwb; C = qpre; N = 1024; xt = bx; }
  else if (bx < 16) { B = kwb; C = kpre; N = 1024; xt = bx - 8; }
  else if (bx < 32) { B = vwb; C = vpre; N = 2048; xt = bx - 16; }
  else              { B = gwb; C = gpre; N = 2048; xt = bx - 32; }
  gemm_body<bf16>(A, B, C, N, 1024, blockIdx.y*128, xt*128);
}

template <typename OutT>
__global__ __launch_bounds__(256) void k_gemm_bt(const bf16* __restrict__ A,
    const bf16* __restrict__ B, OutT* __restrict__ C, int N, int K) {
  gemm_body<OutT>(A, B, C, N, K, blockIdx.y*128, blockIdx.x*128);
}

// ---------------- MFMA chunked delta-rule pre-pass (conv fused) ----------------
template<int NT>
__device__ __forceinline__ void mm_band(const bf16* A_lds, const bf16* B_lds,
    int w16, int cb, int l16, int quad, f32x4* acc) {
#pragma unroll
  for (int n = 0; n < NT; ++n) { acc[n][0]=0.f; acc[n][1]=0.f; acc[n][2]=0.f; acc[n][3]=0.f; }
#pragma unroll
  for (int kt = 0; kt < 2; ++kt) {
    bf16x8 af = *(const bf16x8*)(A_lds + (w16 + l16)*S72 + kt*32 + quad*8);
#pragma unroll
    for (int n = 0; n < NT; ++n) {
      bf16x8 bf = *(const bf16x8*)(B_lds + (cb + n*16 + l16)*S72 + kt*32 + quad*8);
      acc[n] = __builtin_amdgcn_mfma_f32_16x16x32_bf16(af, bf, acc[n], 0, 0, 0);
    }
  }
}

__global__ __launch_bounds__(512) void k_prepass(
    const bf16* __restrict__ qpre, const bf16* __restrict__ kpre,
    const bf16* __restrict__ vpre, const float* __restrict__ cqw,
    const float* __restrict__ ckw, const float* __restrict__ cvw,
    const float* __restrict__ graw, const float* __restrict__ beta,
    bf16* __restrict__ EF, float* __restrict__ dSl, float* __restrict__ obuf) {
  const int bx = blockIdx.x, c = bx >> 4, h = bx & 15, tid = threadIdx.x;
  const int t0 = c * 64;
  const int wave = tid >> 6, lane = tid & 63, l16 = lane & 15, quad = lane >> 4;
  const int w16 = (wave >> 1) * 16;
  const int chh = wave & 1;
  const int r0 = wave * 8;

  __shared__ bf16 SM[50688];
  __shared__ float qf[64*68];
  __shared__ float bs[64], bts_s[64], es[64], gms[64];
  bf16* Kr    = SM;
  bf16* KT    = SM + 4608;
  bf16* KbT   = SM + 9216;
  bf16* Pm    = SM + 13824;
  bf16* powR0 = SM + 18432;
  bf16* powT0 = SM + 23040;
  bf16* powR1 = SM + 27648;
  bf16* powT1 = SM + 32256;
  bf16* prod0 = SM + 36864;
  bf16* prod1 = SM + 41472;
  bf16* T2T   = SM + 46080;
  bf16* VT    = SM + 18432;
  bf16* VlT   = SM + 27648;

  if (tid < 64) {
    float g = graw[(size_t)(t0 + tid)*16 + h];
    float b = g;
#pragma unroll
    for (int off = 1; off < 64; off <<= 1) {
      float p = __shfl_up(b, off, 64);
      if (tid >= off) b += p;
    }
    bs[tid] = b;
    bts_s[tid] = beta[(size_t)(t0 + tid)*16 + h];
    float b63 = __shfl(b, 63, 64);
    es[tid] = __expf(b63 - b);
    gms[tid] = __expf(b);
  }

  float kreg[8], vreg[16];
  {
    float4 wq  = *(const float4*)(cqw + (h*64 + lane)*4);
    float4 wk  = *(const float4*)(ckw + (h*64 + lane)*4);
    float tv[11];
#pragma unroll
    for (int j = 0; j < 11; ++j) {
      int tg = t0 + r0 + j - 3;
      tv[j] = (tg >= 0) ? (float)qpre[(size_t)tg*1024 + h*64 + lane] : 0.f;
    }
#pragma unroll
    for (int rr = 0; rr < 8; ++rr) {
      float y = tv[rr]*wq.x + tv[rr+1]*wq.y + tv[rr+2]*wq.z + tv[rr+3]*wq.w;
      y = y * sigmoidf_(y);
      float ssq = wredsum(y*y);
      y *= rsqrtf(ssq + 1e-6f) * 0.125f;
      qf[(r0+rr)*68 + lane] = y;
    }
#pragma unroll
    for (int j = 0; j < 11; ++j) {
      int tg = t0 + r0 + j - 3;
      tv[j] = (tg >= 0) ? (float)kpre[(size_t)tg*1024 + h*64 + lane] : 0.f;
    }
#pragma unroll
    for (int rr = 0; rr < 8; ++rr) {
      float y = tv[rr]*wk.x + tv[rr+1]*wk.y + tv[rr+2]*wk.z + tv[rr+3]*wk.w;
      y = y * sigmoidf_(y);
      float m = wredsum(y) * (1.f/64.f);
      y -= m;
      float ssq = wredsum(y*y);
      y *= rsqrtf(ssq + 1e-6f);
      kreg[rr] = y;
      bf16 kb = (bf16)y;
      Kr[(r0+rr)*S72 + lane] = kb;
      KT[lane*S72 + (r0+rr)] = kb;
    }
#pragma unroll
    for (int hf = 0; hf < 2; ++hf) {
      float4 wv = *(const float4*)(cvw + (h*128 + hf*64 + lane)*4);
#pragma unroll
      for (int j = 0; j < 11; ++j) {
        int tg = t0 + r0 + j - 3;
        tv[j] = (tg >= 0) ? (float)vpre[(size_t)tg*2048 + h*128 + hf*64 + lane] : 0.f;
      }
#pragma unroll
      for (int rr = 0; rr < 8; ++rr) {
        float y = tv[rr]*wv.x + tv[rr+1]*wv.y + tv[rr+2]*wv.z + tv[rr+3]*wv.w;
        vreg[hf*8+rr] = y * sigmoidf_(y);
      }
    }
  }
  __syncthreads();
#pragma unroll
  for (int rr = 0; rr < 8; ++rr)
    KbT[lane*S72 + (r0+rr)] = (bf16)(kreg[rr] * es[r0+rr]);

  // A-build
  {
    f32x4 acc[2];
    mm_band<2>(Kr, Kr, w16, chh*32, l16, quad, acc);
#pragma unroll
    for (int n = 0; n < 2; ++n) {
      int col = chh*32 + n*16 + l16;
      bf16x4v tv;
#pragma unroll
      for (int r = 0; r < 4; ++r) {
        int row = w16 + quad*4 + r;
        float nv = 0.f;
        if (row > col) nv = -bts_s[row] * __expf(bs[row] - bs[col]) * acc[n][r];
        bf16 nb = (bf16)nv;
        powR0[row*S72 + col] = nb;
        tv[r] = nb;
        prod0[row*S72 + col] = (row == col) ? (bf16)1.f : nb;
      }
      *(bf16x4v*)(powT0 + col*S72 + w16 + quad*4) = tv;
    }
  }
  // P-build
  {
    f32x4 acc[2];
#pragma unroll
    for (int n = 0; n < 2; ++n) { acc[n][0]=0.f; acc[n][1]=0.f; acc[n][2]=0.f; acc[n][3]=0.f; }
#pragma unroll
    for (int kt = 0; kt < 2; ++kt) {
      const float* qp = qf + (w16 + l16)*68 + kt*32 + quad*8;
      float4 a4 = *(const float4*)qp;
      float4 b4 = *(const float4*)(qp + 4);
      bf16x8 af;
      af[0]=(bf16)a4.x; af[1]=(bf16)a4.y; af[2]=(bf16)a4.z; af[3]=(bf16)a4.w;
      af[4]=(bf16)b4.x; af[5]=(bf16)b4.y; af[6]=(bf16)b4.z; af[7]=(bf16)b4.w;
#pragma unroll
      for (int n = 0; n < 2; ++n) {
        bf16x8 bf = *(const bf16x8*)(Kr + (chh*32 + n*16 + l16)*S72 + kt*32 + quad*8);
        acc[n] = __builtin_amdgcn_mfma_f32_16x16x32_bf16(af, bf, acc[n], 0, 0, 0);
      }
    }
#pragma unroll
    for (int n = 0; n < 2; ++n) {
      int col = chh*32 + n*16 + l16;
#pragma unroll
      for (int r = 0; r < 4; ++r) {
        int row = w16 + quad*4 + r;
        float pv = (row >= col) ? __expf(bs[row] - bs[col]) * acc[n][r] : 0.f;
        Pm[row*S72 + col] = (bf16)pv;
      }
    }
  }
  __syncthreads();

  // squaring chain: (I+A)^-1
  int pc = 0, rc = 0;
#pragma unroll 1
  for (int i = 1; i <= 5; ++i) {
    bf16* sqA = pc ? powR1 : powR0;
    bf16* sqB = pc ? powT1 : powT0;
    bf16* sqRo = pc ? powR0 : powR1;
    bf16* sqTo = pc ? powT0 : powT1;
    {
      f32x4 acc[2];
      mm_band<2>(sqA, sqB, w16, chh*32, l16, quad, acc);
#pragma unroll
      for (int n = 0; n < 2; ++n) {
        int col = chh*32 + n*16 + l16;
        bf16x4v tv;
#pragma unroll
        for (int r = 0; r < 4; ++r) {
          int row = w16 + quad*4 + r;
          bf16 vb = (bf16)acc[n][r];
          sqRo[row*S72 + col] = vb;
          tv[r] = vb;
        }
        *(bf16x4v*)(sqTo + col*S72 + w16 + quad*4) = tv;
      }
    }
    __syncthreads();
    bf16* prA = rc ? prod1 : prod0;
    bf16* prO = rc ? prod0 : prod1;
    {
      f32x4 acc[2];
      mm_band<2>(prA, sqTo, w16, chh*32, l16, quad, acc);
#pragma unroll
      for (int n = 0; n < 2; ++n) {
        int col = chh*32 + n*16 + l16;
        bf16x4v tv;
#pragma unroll
        for (int r = 0; r < 4; ++r) {
          int row = w16 + quad*4 + r;
          float val = acc[n][r] + (float)prA[row*S72 + col];
          prO[row*S72 + col] = (bf16)val;
          tv[r] = (bf16)(val * bts_s[col] * gms[col]);
        }
        if (i == 5) *(bf16x4v*)(T2T + col*S72 + w16 + quad*4) = tv;
      }
    }
    __syncthreads();
    pc ^= 1; rc ^= 1;
  }
  bf16* Mrow = rc ? prod1 : prod0;
  bf16* WR   = rc ? prod0 : prod1;

#pragma unroll
  for (int hf = 0; hf < 2; ++hf)
#pragma unroll
    for (int rr = 0; rr < 8; ++rr)
      VT[(hf*64 + lane)*S72 + (r0+rr)] = (bf16)(bts_s[r0+rr] * vreg[hf*8+rr]);
  __syncthreads();

  // V_loc^T
  {
    f32x4 acc[4];
    mm_band<4>(Mrow, VT, w16, chh*64, l16, quad, acc);
#pragma unroll
    for (int n = 0; n < 4; ++n) {
      int col = chh*64 + n*16 + l16;
      bf16x4v tv;
#pragma unroll
      for (int r = 0; r < 4; ++r) tv[r] = (bf16)acc[n][r];
      *(bf16x4v*)(VlT + col*S72 + w16 + quad*4) = tv;
    }
  }
  __syncthreads();

  // dS_loc
  {
    f32x4 acc[4];
    mm_band<4>(KbT, VlT, w16, chh*64, l16, quad, acc);
#pragma unroll
    for (int n = 0; n < 4; ++n) {
      int col = chh*64 + n*16 + l16;
#pragma unroll
      for (int r = 0; r < 4; ++r)
        dSl[(size_t)bx*8192 + (size_t)(w16 + quad*4 + r)*128 + col] = acc[n][r];
    }
  }
  // W2 = Kbar^T T2
  {
    f32x4 acc[2];
    mm_band<2>(KbT, T2T, w16, chh*32, l16, quad, acc);
#pragma unroll
    for (int n = 0; n < 2; ++n) {
      int col = chh*32 + n*16 + l16;
#pragma unroll
      for (int r = 0; r < 4; ++r)
        WR[(w16 + quad*4 + r)*S72 + col] = (bf16)acc[n][r];
    }
  }
  __syncthreads();
  // E
  {
    f32x4 acc[2];
    mm_band<2>(WR, KT, w16, chh*32, l16, quad, acc);
    float gC = gms[63];
    size_t eb = (size_t)bx * 13824;
#pragma unroll
    for (int n = 0; n < 2; ++n) {
      int col = chh*32 + n*16 + l16;
#pragma unroll
      for (int r = 0; r < 4; ++r) {
        int row = w16 + quad*4 + r;
        float ev = ((row == col) ? gC : 0.f) - acc[n][r];
        bf16 eh = (bf16)ev;
        EF[eb + row*S72 + col] = eh;
        EF[eb + 4608 + row*S72 + col] = (bf16)(ev - (float)eh);
      }
    }
  }
  __syncthreads();
  // R = P T2
  {
    f32x4 acc[2];
    mm_band<2>(Pm, T2T, w16, chh*32, l16, quad, acc);
#pragma unroll
    for (int n = 0; n < 2; ++n) {
      int col = chh*32 + n*16 + l16;
#pragma unroll
      for (int r = 0; r < 4; ++r)
        WR[(w16 + quad*4 + r)*S72 + col] = (bf16)acc[n][r];
    }
  }
  __syncthreads();
  // F
  {
    f32x4 acc[2];
    mm_band<2>(WR, KT, w16, chh*32, l16, quad, acc);
    size_t eb = (size_t)bx * 13824;
#pragma unroll
    for (int n = 0; n < 2; ++n) {
      int col = chh*32 + n*16 + l16;
#pragma unroll
      for (int r = 0; r < 4; ++r) {
        int row = w16 + quad*4 + r;
        float qv = qf[row*68 + col];
        EF[eb + 9216 + row*S72 + col] = (bf16)(gms[row]*qv - acc[n][r]);
      }
    }
  }
  // O_loc
  {
    f32x4 acc[4];
    mm_band<4>(Pm, VlT, w16, chh*64, l16, quad, acc);
#pragma unroll
    for (int n = 0; n < 4; ++n) {
      int col = chh*64 + n*16 + l16;
#pragma unroll
      for (int r = 0; r < 4; ++r)
        obuf[(size_t)(t0 + w16 + quad*4 + r)*2048 + h*128 + col] = acc[n][r];
    }
  }
}

// ---------------- MFMA sequential recurrence + fused gated RMSNorm ----------------
// grid 16 = one block per head, 512 threads (8 waves = 4 DK-bands x 2 DV-halves).
// E/F/dS fetched as per-lane register fragments (no LDS DMA), prefetched 1 chunk ahead.
__global__ __launch_bounds__(512) void k_seq(const bf16* __restrict__ EF,
    const float* __restrict__ dSl, const float* __restrict__ ob,
    const bf16* __restrict__ gpre, const float* __restrict__ onw,
    bf16* __restrict__ ogb) {
  const int h = blockIdx.x;
  const int tid = threadIdx.x, wave = tid >> 6, lane = tid & 63;
  const int l16 = lane & 15, quad = lane >> 4;
  const int mb = (wave >> 1) * 16, dvh = wave & 1;
  __shared__ bf16 Sthi[128*S72], Stlo[128*S72];
  __shared__ float osL[64*132];
  const int erow = tid >> 3, eseg = tid & 7;
  float wreg[16];
#pragma unroll
  for (int i = 0; i < 4; ++i)
    *(float4*)(wreg + i*4) = *(const float4*)(onw + eseg*16 + i*4);
  for (int i = tid; i < 9216; i += 512) { Sthi[i] = (bf16)0.f; Stlo[i] = (bf16)0.f; }
  bf16x8 feh[2], fel[2], fff[2];
  float dsv[16];
  {
    const bf16* ef = EF + (size_t)h * 13824;
#pragma unroll
    for (int kt = 0; kt < 2; ++kt) {
      feh[kt] = *(const bf16x8*)(ef +        (mb + l16)*S72 + kt*32 + quad*8);
      fel[kt] = *(const bf16x8*)(ef + 4608 + (mb + l16)*S72 + kt*32 + quad*8);
      fff[kt] = *(const bf16x8*)(ef + 9216 + (mb + l16)*S72 + kt*32 + quad*8);
    }
    size_t base = (size_t)h*8192;
#pragma unroll
    for (int nt = 0; nt < 4; ++nt)
#pragma unroll
      for (int r = 0; r < 4; ++r)
        dsv[nt*4+r] = dSl[base + (size_t)(mb+quad*4+r)*128 + dvh*64 + nt*16 + l16];
  }
  __syncthreads();
#pragma unroll 1
  for (int c = 0; c < 32; ++c) {
    bf16x8 neh[2], nel[2], nff[2];
    float dsn[16] = {};
    if (c + 1 < 32) {
      const bf16* ef = EF + (size_t)((c+1)*16 + h) * 13824;
#pragma unroll
      for (int kt = 0; kt < 2; ++kt) {
        neh[kt] = *(const bf16x8*)(ef +        (mb + l16)*S72 + kt*32 + quad*8);
        nel[kt] = *(const bf16x8*)(ef + 4608 + (mb + l16)*S72 + kt*32 + quad*8);
        nff[kt] = *(const bf16x8*)(ef + 9216 + (mb + l16)*S72 + kt*32 + quad*8);
      }
      size_t base = (size_t)((c+1)*16 + h)*8192;
#pragma unroll
      for (int nt = 0; nt < 4; ++nt)
#pragma unroll
        for (int r = 0; r < 4; ++r)
          dsn[nt*4+r] = dSl[base + (size_t)(mb+quad*4+r)*128 + dvh*64 + nt*16 + l16];
    } else {
#pragma unroll
      for (int kt = 0; kt < 2; ++kt) { neh[kt] = feh[kt]; nel[kt] = fel[kt]; nff[kt] = fff[kt]; }
    }
    // epilogue operand prefetch for current chunk
    float obr[16]; bf16x8 gr0, gr1;
    {
      size_t base = (size_t)(c*64 + erow)*2048 + h*128 + eseg*16;
#pragma unroll
      for (int i = 0; i < 4; ++i)
        *(float4*)(obr + i*4) = *(const float4*)(ob + base + i*4);
      gr0 = *(const bf16x8*)(gpre + base);
      gr1 = *(const bf16x8*)(gpre + base + 8);
    }
    f32x4 accS[4], accO[4];
#pragma unroll
    for (int nt = 0; nt < 4; ++nt) {
#pragma unroll
      for (int r = 0; r < 4; ++r) accS[nt][r] = dsv[nt*4+r];
      accO[nt][0]=0.f; accO[nt][1]=0.f; accO[nt][2]=0.f; accO[nt][3]=0.f;
    }
#pragma unroll
    for (int kt = 0; kt < 2; ++kt)
#pragma unroll
      for (int nt = 0; nt < 4; ++nt) {
        int col = dvh*64 + nt*16 + l16;
        bf16x8 sh = *(const bf16x8*)(Sthi + col*S72 + kt*32 + quad*8);
        bf16x8 sl = *(const bf16x8*)(Stlo + col*S72 + kt*32 + quad*8);
        accS[nt] = __builtin_amdgcn_mfma_f32_16x16x32_bf16(feh[kt], sh, accS[nt], 0, 0, 0);
        accS[nt] = __builtin_amdgcn_mfma_f32_16x16x32_bf16(feh[kt], sl, accS[nt], 0, 0, 0);
        accS[nt] = __builtin_amdgcn_mfma_f32_16x16x32_bf16(fel[kt], sh, accS[nt], 0, 0, 0);
        accO[nt] = __builtin_amdgcn_mfma_f32_16x16x32_bf16(fff[kt], sh, accO[nt], 0, 0, 0);
        accO[nt] = __builtin_amdgcn_mfma_f32_16x16x32_bf16(fff[kt], sl, accO[nt], 0, 0, 0);
      }
    __syncthreads();   // all St reads done
#pragma unroll
    for (int nt = 0; nt < 4; ++nt) {
      int col = dvh*64 + nt*16 + l16;
      bf16x4v hv, lv;
#pragma unroll
      for (int r = 0; r < 4; ++r) {
        float v = accS[nt][r];
        bf16 hb = (bf16)v; hv[r] = hb; lv[r] = (bf16)(v - (float)hb);
        osL[(mb+quad*4+r)*132 + col] = accO[nt][r];
      }
      *(bf16x4v*)(Sthi + col*S72 + mb + quad*4) = hv;
      *(bf16x4v*)(Stlo + col*S72 + mb + quad*4) = lv;
    }
    __syncthreads();   // St + osL visible
    // fused gated RMSNorm epilogue: thread owns (row=erow, 16 cols at eseg*16)
    {
      float vals[16]; float ssq = 0.f;
#pragma unroll
      for (int i = 0; i < 16; ++i) {
        float v = obr[i] + osL[erow*132 + eseg*16 + i];
        vals[i] = v; ssq += v*v;
      }
      ssq += __shfl_xor(ssq, 1, 64);
      ssq += __shfl_xor(ssq, 2, 64);
      ssq += __shfl_xor(ssq, 4, 64);
      float rsn = rsqrtf(ssq * (1.f/128.f) + 1e-5f);
      bf16x8 o0, o1;
#pragma unroll
      for (int i = 0; i < 16; ++i) {
        float g = (float)((i < 8) ? gr0[i] : gr1[i-8]);
        float r = vals[i] * rsn * wreg[i] * (g * sigmoidf_(g));
        if (i < 8) o0[i] = (bf16)r; else o1[i-8] = (bf16)r;
      }
      size_t base = (size_t)(c*64 + erow)*2048 + h*128 + eseg*16;
      *(bf16x8*)(ogb + base) = o0;
      *(bf16x8*)(ogb + base + 8) = o1;
    }
#pragma unroll
    for (int kt = 0; kt < 2; ++kt) { feh[kt]=neh[kt]; fel[kt]=nel[kt]; fff[kt]=nff[kt]; }
#pragma unroll
    for (int i = 0; i < 16; ++i) dsv[i] = dsn[i];
  }
}

extern "C" void kernel_launch(void* const* d_in, const int* in_sizes, int n_in,
                              void* d_out, int out_size, void* d_ws, size_t ws_size,
                              hipStream_t stream) {
  const float* hs   = (const float*)d_in[0];
  const float* nw   = (const float*)d_in[1];
  const float* qw   = (const float*)d_in[2];
  const float* kw   = (const float*)d_in[3];
  const float* vw   = (const float*)d_in[4];
  const float* aw   = (const float*)d_in[5];
  const float* bw   = (const float*)d_in[6];
  const float* gw   = (const float*)d_in[7];
  const float* dtb  = (const float*)d_in[8];
  const float* alog = (const float*)d_in[9];
  const float* cqw  = (const float*)d_in[10];
  const float* ckw  = (const float*)d_in[11];
  const float* cvw  = (const float*)d_in[12];
  const float* onw  = (const float*)d_in[13];
  const float* opw  = (const float*)d_in[14];
  const float* ow   = (const float*)d_in[15];
  float* out = (float*)d_out;

  char* p = (char*)d_ws;
  auto alloc = [&](size_t bytes) { char* r = p; p += (bytes + 255) & ~255ull; return r; };
  bf16*  xb    = (bf16*) alloc((size_t)2048*1024*2);   // } dSl aliases xb..gwb (16 MB,
  bf16*  qwb   = (bf16*) alloc((size_t)1024*1024*2);   // } all dead after k_gemm_proj)
  bf16*  kwb   = (bf16*) alloc((size_t)1024*1024*2);
  bf16*  vwb   = (bf16*) alloc((size_t)2048*1024*2);
  bf16*  gwb   = (bf16*) alloc((size_t)2048*1024*2);
  bf16*  opwb  = (bf16*) alloc((size_t)1024*2048*2);
  bf16*  owb   = (bf16*) alloc((size_t)1024*1024*2);
  bf16*  qpre  = (bf16*) alloc((size_t)2048*1024*2);
  bf16*  kpre  = (bf16*) alloc((size_t)2048*1024*2);
  bf16*  vpre  = (bf16*) alloc((size_t)2048*2048*2);
  bf16*  gpre  = (bf16*) alloc((size_t)2048*2048*2);
  float* graw  = (float*)alloc((size_t)2048*16*4);
  float* btb   = (float*)alloc((size_t)2048*16*4);
  float* ob    = (float*)alloc((size_t)2048*2048*4);
  bf16*  ogb   = (bf16*) alloc((size_t)2048*2048*2);
  bf16*  h1b   = (bf16*) alloc((size_t)2048*1024*2);
  bf16*  EF    = (bf16*) alloc((size_t)512*13824*2);
  float* dSl   = (float*)xb;   // 16 MB over xb..gwb (dead after k_gemm_proj)

  k_rmsnorm<<<2048, 256, 0, stream>>>(hs, nw, aw, bw, dtb, alog, xb, graw, btb);
  k_castw<<<4608, 256, 0, stream>>>(qw, kw, vw, gw, opw, ow, qwb, kwb, vwb, gwb, opwb, owb);
  k_gemm_proj<<<dim3(48,16,1), 256, 0, stream>>>(xb, qwb, kwb, vwb, gwb, qpre, kpre, vpre, gpre);
  k_prepass<<<512, 512, 0, stream>>>(qpre, kpre, vpre, cqw, ckw, cvw, graw, btb, EF, dSl, ob);
  k_seq<<<16, 512, 0, stream>>>(EF, dSl, ob, gpre, onw, ogb);
  k_gemm_bt<bf16><<<dim3(8,16,1), 256, 0, stream>>>(ogb, opwb, h1b, 1024, 2048);
  k_gemm_bt<float><<<dim3(8,16,1), 256, 0, stream>>>(h1b, owb, out, 1024, 1024);
}

// Round 7
// 311.882 us; speedup vs baseline: 1.1941x; 1.1941x over previous
//
#include <hip/hip_runtime.h>
#include <math.h>

#define TT 2048
#define S72 72

typedef __bf16 bf16;
typedef __bf16 bf16x8 __attribute__((ext_vector_type(8)));
typedef __bf16 bf16x4v __attribute__((ext_vector_type(4)));
typedef __bf16 bf16x2v __attribute__((ext_vector_type(2)));
typedef float f32x4 __attribute__((ext_vector_type(4)));

__device__ __forceinline__ float wredsum(float v) {
#pragma unroll
  for (int off = 32; off > 0; off >>= 1) v += __shfl_xor(v, off, 64);
  return v;
}
__device__ __forceinline__ float sigmoidf_(float x) { return 1.f / (1.f + __expf(-x)); }

// ---------------- RMSNorm + a/b projections fused ----------------
__global__ __launch_bounds__(256) void k_rmsnorm(const float* __restrict__ h,
    const float* __restrict__ nw, const float* __restrict__ aw,
    const float* __restrict__ bw, const float* __restrict__ dtb,
    const float* __restrict__ alog, bf16* __restrict__ xb,
    float* __restrict__ graw, float* __restrict__ btb) {
  int t = blockIdx.x, tid = threadIdx.x;
  float4 hv = *(const float4*)(h + (size_t)t*1024 + tid*4);
  float ss = hv.x*hv.x + hv.y*hv.y + hv.z*hv.z + hv.w*hv.w;
  __shared__ float red[4];
  __shared__ __align__(16) float xs[1024];
  float wsum = wredsum(ss);
  if ((tid & 63) == 0) red[tid >> 6] = wsum;
  __syncthreads();
  float tot = red[0] + red[1] + red[2] + red[3];
  float rs = rsqrtf(tot * (1.f/1024.f) + 1e-6f);
  float4 w4 = *(const float4*)(nw + tid*4);
  float4 y;
  y.x = hv.x*rs*w4.x; y.y = hv.y*rs*w4.y; y.z = hv.z*rs*w4.z; y.w = hv.w*rs*w4.w;
  *(float4*)(xs + tid*4) = y;
  bf16x4v b; b[0]=(bf16)y.x; b[1]=(bf16)y.y; b[2]=(bf16)y.z; b[3]=(bf16)y.w;
  *(bf16x4v*)(xb + (size_t)t*1024 + tid*4) = b;
  __syncthreads();
  int wave = tid >> 6, lane = tid & 63;
  const float4* x4 = (const float4*)xs;
#pragma unroll
  for (int hi = 0; hi < 4; ++hi) {
    int hh = wave*4 + hi;
    float sa = 0.f, sb = 0.f;
#pragma unroll
    for (int i = 0; i < 4; ++i) {
      float4 xv = x4[i*64 + lane];
      float4 av = *(const float4*)(aw + hh*1024 + i*256 + lane*4);
      float4 bv = *(const float4*)(bw + hh*1024 + i*256 + lane*4);
      sa += xv.x*av.x + xv.y*av.y + xv.z*av.z + xv.w*av.w;
      sb += xv.x*bv.x + xv.y*bv.y + xv.z*bv.z + xv.w*bv.w;
    }
    sa = wredsum(sa); sb = wredsum(sb);
    if (lane == 0) {
      float ap = sa + dtb[hh];
      float sp = (ap > 20.f) ? ap : log1pf(expf(ap));
      graw[t*16 + hh] = -expf(alog[hh]) * sp;
      btb[t*16 + hh] = 1.f / (1.f + expf(-sb));
    }
  }
}

// ---------------- cast weights f32 -> bf16 (6 tensors) ----------------
__global__ void k_castw(const float* __restrict__ qw, const float* __restrict__ kw,
    const float* __restrict__ vw, const float* __restrict__ gw,
    const float* __restrict__ opw, const float* __restrict__ ow,
    bf16* qwb, bf16* kwb, bf16* vwb, bf16* gwb, bf16* opwb, bf16* owb) {
  for (long u = (long)blockIdx.x*256 + threadIdx.x; u < 2359296; u += (long)gridDim.x*256) {
    const float* src; bf16* dst; long l;
    if      (u <  262144) { src=qw;  dst=qwb;  l=u; }
    else if (u <  524288) { src=kw;  dst=kwb;  l=u-262144; }
    else if (u < 1048576) { src=vw;  dst=vwb;  l=u-524288; }
    else if (u < 1572864) { src=gw;  dst=gwb;  l=u-1048576; }
    else if (u < 2097152) { src=opw; dst=opwb; l=u-1572864; }
    else                  { src=ow;  dst=owb;  l=u-2097152; }
    float4 s = *(const float4*)(src + l*4);
    bf16x4v b; b[0]=(bf16)s.x; b[1]=(bf16)s.y; b[2]=(bf16)s.z; b[3]=(bf16)s.w;
    *(bf16x4v*)(dst + l*4) = b;
  }
}

// ---------------- bf16 MFMA GEMM (double-buffered, XOR-swizzled) ----------------
template <typename OutT>
__device__ __forceinline__ void gemm_body(const bf16* __restrict__ A,
    const bf16* __restrict__ B, OutT* __restrict__ C, int N, int K, int m0, int n0) {
  __shared__ bf16 As[2][128*32];
  __shared__ bf16 Bs[2][128*32];
  const int tid = threadIdx.x, lane = tid & 63, wave = tid >> 6;
  const int wm = (wave >> 1) * 64, wn = (wave & 1) * 64;
  const int srow = wave*16 + (lane >> 2);
  const int swl = (((lane & 3) ^ ((lane >> 3) & 3))) * 8;
  const int sdst = (lane & 3) * 8;
  const int quad = lane >> 4, l16 = lane & 15;
  const int sw = (l16 >> 1) & 3;
  f32x4 acc[4][4] = {};
  const int nk = K >> 5;
#pragma unroll
  for (int i = 0; i < 2; ++i) {
    int r = i*64 + srow;
    __builtin_amdgcn_global_load_lds(
      (__attribute__((address_space(1))) void*)(A + (size_t)(m0 + r)*K + swl),
      (__attribute__((address_space(3))) void*)(&As[0][r*32 + sdst]), 16, 0, 0);
    __builtin_amdgcn_global_load_lds(
      (__attribute__((address_space(1))) void*)(B + (size_t)(n0 + r)*K + swl),
      (__attribute__((address_space(3))) void*)(&Bs[0][r*32 + sdst]), 16, 0, 0);
  }
  for (int kt = 0; kt < nk; ++kt) {
    const int cur = kt & 1;
    __syncthreads();
    bf16x8 af[4], bfr[4];
#pragma unroll
    for (int mt = 0; mt < 4; ++mt)
      af[mt] = *(const bf16x8*)(&As[cur][(wm + mt*16 + l16)*32 + (quad ^ sw)*8]);
#pragma unroll
    for (int nt = 0; nt < 4; ++nt)
      bfr[nt] = *(const bf16x8*)(&Bs[cur][(wn + nt*16 + l16)*32 + (quad ^ sw)*8]);
    if (kt + 1 < nk) {
      int k0 = (kt + 1) << 5;
#pragma unroll
      for (int i = 0; i < 2; ++i) {
        int r = i*64 + srow;
        __builtin_amdgcn_global_load_lds(
          (__attribute__((address_space(1))) void*)(A + (size_t)(m0 + r)*K + k0 + swl),
          (__attribute__((address_space(3))) void*)(&As[cur^1][r*32 + sdst]), 16, 0, 0);
        __builtin_amdgcn_global_load_lds(
          (__attribute__((address_space(1))) void*)(B + (size_t)(n0 + r)*K + k0 + swl),
          (__attribute__((address_space(3))) void*)(&Bs[cur^1][r*32 + sdst]), 16, 0, 0);
      }
    }
#pragma unroll
    for (int mt = 0; mt < 4; ++mt)
#pragma unroll
      for (int nt = 0; nt < 4; ++nt)
        acc[mt][nt] = __builtin_amdgcn_mfma_f32_16x16x32_bf16(af[mt], bfr[nt], acc[mt][nt], 0, 0, 0);
  }
#pragma unroll
  for (int mt = 0; mt < 4; ++mt)
#pragma unroll
    for (int nt = 0; nt < 4; ++nt)
#pragma unroll
      for (int r = 0; r < 4; ++r) {
        int row = m0 + wm + mt*16 + quad*4 + r;
        int col = n0 + wn + nt*16 + l16;
        C[(size_t)row*N + col] = (OutT)acc[mt][nt][r];
      }
}

__global__ __launch_bounds__(256) void k_gemm_proj(const bf16* __restrict__ A,
    const bf16* __restrict__ qwb, const bf16* __restrict__ kwb,
    const bf16* __restrict__ vwb, const bf16* __restrict__ gwb,
    bf16* __restrict__ qpre, bf16* __restrict__ kpre,
    bf16* __restrict__ vpre, bf16* __restrict__ gpre) {
  int bx = blockIdx.x;
  const bf16* B; bf16* C; int N, xt;
  if      (bx <  8) { B = qwb; C = qpre; N = 1024; xt = bx; }
  else if (bx < 16) { B = kwb; C = kpre; N = 1024; xt = bx - 8; }
  else if (bx < 32) { B = vwb; C = vpre; N = 2048; xt = bx - 16; }
  else              { B = gwb; C = gpre; N = 2048; xt = bx - 32; }
  gemm_body<bf16>(A, B, C, N, 1024, blockIdx.y*128, xt*128);
}

template <typename OutT>
__global__ __launch_bounds__(256) void k_gemm_bt(const bf16* __restrict__ A,
    const bf16* __restrict__ B, OutT* __restrict__ C, int N, int K) {
  gemm_body<OutT>(A, B, C, N, K, blockIdx.y*128, blockIdx.x*128);
}

// ---------------- MFMA chunked delta-rule pre-pass (conv fused) ----------------
template<int NT>
__device__ __forceinline__ void mm_band(const bf16* A_lds, const bf16* B_lds,
    int w16, int cb, int l16, int quad, f32x4* acc) {
#pragma unroll
  for (int n = 0; n < NT; ++n) { acc[n][0]=0.f; acc[n][1]=0.f; acc[n][2]=0.f; acc[n][3]=0.f; }
#pragma unroll
  for (int kt = 0; kt < 2; ++kt) {
    bf16x8 af = *(const bf16x8*)(A_lds + (w16 + l16)*S72 + kt*32 + quad*8);
#pragma unroll
    for (int n = 0; n < NT; ++n) {
      bf16x8 bf = *(const bf16x8*)(B_lds + (cb + n*16 + l16)*S72 + kt*32 + quad*8);
      acc[n] = __builtin_amdgcn_mfma_f32_16x16x32_bf16(af, bf, acc[n], 0, 0, 0);
    }
  }
}

__global__ __launch_bounds__(512) void k_prepass(
    const bf16* __restrict__ qpre, const bf16* __restrict__ kpre,
    const bf16* __restrict__ vpre, const float* __restrict__ cqw,
    const float* __restrict__ ckw, const float* __restrict__ cvw,
    const float* __restrict__ graw, const float* __restrict__ beta,
    bf16* __restrict__ EF, float* __restrict__ dSl, float* __restrict__ obuf) {
  const int bx = blockIdx.x, c = bx >> 4, h = bx & 15, tid = threadIdx.x;
  const int t0 = c * 64;
  const int wave = tid >> 6, lane = tid & 63, l16 = lane & 15, quad = lane >> 4;
  const int w16 = (wave >> 1) * 16;
  const int chh = wave & 1;
  const int r0 = wave * 8;

  __shared__ bf16 SM[50688];
  __shared__ float qf[64*68];
  __shared__ float bs[64], bts_s[64], es[64], gms[64];
  bf16* Kr    = SM;
  bf16* KT    = SM + 4608;
  bf16* KbT   = SM + 9216;
  bf16* Pm    = SM + 13824;
  bf16* powR0 = SM + 18432;
  bf16* powT0 = SM + 23040;
  bf16* powR1 = SM + 27648;
  bf16* powT1 = SM + 32256;
  bf16* prod0 = SM + 36864;
  bf16* prod1 = SM + 41472;
  bf16* T2T   = SM + 46080;
  bf16* VT    = SM + 18432;
  bf16* VlT   = SM + 27648;

  if (tid < 64) {
    float g = graw[(size_t)(t0 + tid)*16 + h];
    float b = g;
#pragma unroll
    for (int off = 1; off < 64; off <<= 1) {
      float p = __shfl_up(b, off, 64);
      if (tid >= off) b += p;
    }
    bs[tid] = b;
    bts_s[tid] = beta[(size_t)(t0 + tid)*16 + h];
    float b63 = __shfl(b, 63, 64);
    es[tid] = __expf(b63 - b);
    gms[tid] = __expf(b);
  }

  float kreg[8], vreg[16];
  {
    float4 wq  = *(const float4*)(cqw + (h*64 + lane)*4);
    float4 wk  = *(const float4*)(ckw + (h*64 + lane)*4);
    float tv[11];
#pragma unroll
    for (int j = 0; j < 11; ++j) {
      int tg = t0 + r0 + j - 3;
      tv[j] = (tg >= 0) ? (float)qpre[(size_t)tg*1024 + h*64 + lane] : 0.f;
    }
#pragma unroll
    for (int rr = 0; rr < 8; ++rr) {
      float y = tv[rr]*wq.x + tv[rr+1]*wq.y + tv[rr+2]*wq.z + tv[rr+3]*wq.w;
      y = y * sigmoidf_(y);
      float ssq = wredsum(y*y);
      y *= rsqrtf(ssq + 1e-6f) * 0.125f;
      qf[(r0+rr)*68 + lane] = y;
    }
#pragma unroll
    for (int j = 0; j < 11; ++j) {
      int tg = t0 + r0 + j - 3;
      tv[j] = (tg >= 0) ? (float)kpre[(size_t)tg*1024 + h*64 + lane] : 0.f;
    }
#pragma unroll
    for (int rr = 0; rr < 8; ++rr) {
      float y = tv[rr]*wk.x + tv[rr+1]*wk.y + tv[rr+2]*wk.z + tv[rr+3]*wk.w;
      y = y * sigmoidf_(y);
      float m = wredsum(y) * (1.f/64.f);
      y -= m;
      float ssq = wredsum(y*y);
      y *= rsqrtf(ssq + 1e-6f);
      kreg[rr] = y;
      bf16 kb = (bf16)y;
      Kr[(r0+rr)*S72 + lane] = kb;
      KT[lane*S72 + (r0+rr)] = kb;
    }
#pragma unroll
    for (int hf = 0; hf < 2; ++hf) {
      float4 wv = *(const float4*)(cvw + (h*128 + hf*64 + lane)*4);
#pragma unroll
      for (int j = 0; j < 11; ++j) {
        int tg = t0 + r0 + j - 3;
        tv[j] = (tg >= 0) ? (float)vpre[(size_t)tg*2048 + h*128 + hf*64 + lane] : 0.f;
      }
#pragma unroll
      for (int rr = 0; rr < 8; ++rr) {
        float y = tv[rr]*wv.x + tv[rr+1]*wv.y + tv[rr+2]*wv.z + tv[rr+3]*wv.w;
        vreg[hf*8+rr] = y * sigmoidf_(y);
      }
    }
  }
  __syncthreads();
#pragma unroll
  for (int rr = 0; rr < 8; ++rr)
    KbT[lane*S72 + (r0+rr)] = (bf16)(kreg[rr] * es[r0+rr]);

  // A-build
  {
    f32x4 acc[2];
    mm_band<2>(Kr, Kr, w16, chh*32, l16, quad, acc);
#pragma unroll
    for (int n = 0; n < 2; ++n) {
      int col = chh*32 + n*16 + l16;
      bf16x4v tv;
#pragma unroll
      for (int r = 0; r < 4; ++r) {
        int row = w16 + quad*4 + r;
        float nv = 0.f;
        if (row > col) nv = -bts_s[row] * __expf(bs[row] - bs[col]) * acc[n][r];
        bf16 nb = (bf16)nv;
        powR0[row*S72 + col] = nb;
        tv[r] = nb;
        prod0[row*S72 + col] = (row == col) ? (bf16)1.f : nb;
      }
      *(bf16x4v*)(powT0 + col*S72 + w16 + quad*4) = tv;
    }
  }
  // P-build
  {
    f32x4 acc[2];
#pragma unroll
    for (int n = 0; n < 2; ++n) { acc[n][0]=0.f; acc[n][1]=0.f; acc[n][2]=0.f; acc[n][3]=0.f; }
#pragma unroll
    for (int kt = 0; kt < 2; ++kt) {
      const float* qp = qf + (w16 + l16)*68 + kt*32 + quad*8;
      float4 a4 = *(const float4*)qp;
      float4 b4 = *(const float4*)(qp + 4);
      bf16x8 af;
      af[0]=(bf16)a4.x; af[1]=(bf16)a4.y; af[2]=(bf16)a4.z; af[3]=(bf16)a4.w;
      af[4]=(bf16)b4.x; af[5]=(bf16)b4.y; af[6]=(bf16)b4.z; af[7]=(bf16)b4.w;
#pragma unroll
      for (int n = 0; n < 2; ++n) {
        bf16x8 bf = *(const bf16x8*)(Kr + (chh*32 + n*16 + l16)*S72 + kt*32 + quad*8);
        acc[n] = __builtin_amdgcn_mfma_f32_16x16x32_bf16(af, bf, acc[n], 0, 0, 0);
      }
    }
#pragma unroll
    for (int n = 0; n < 2; ++n) {
      int col = chh*32 + n*16 + l16;
#pragma unroll
      for (int r = 0; r < 4; ++r) {
        int row = w16 + quad*4 + r;
        float pv = (row >= col) ? __expf(bs[row] - bs[col]) * acc[n][r] : 0.f;
        Pm[row*S72 + col] = (bf16)pv;
      }
    }
  }
  __syncthreads();

  // squaring chain: (I+A)^-1
  int pc = 0, rc = 0;
#pragma unroll 1
  for (int i = 1; i <= 5; ++i) {
    bf16* sqA = pc ? powR1 : powR0;
    bf16* sqB = pc ? powT1 : powT0;
    bf16* sqRo = pc ? powR0 : powR1;
    bf16* sqTo = pc ? powT0 : powT1;
    {
      f32x4 acc[2];
      mm_band<2>(sqA, sqB, w16, chh*32, l16, quad, acc);
#pragma unroll
      for (int n = 0; n < 2; ++n) {
        int col = chh*32 + n*16 + l16;
        bf16x4v tv;
#pragma unroll
        for (int r = 0; r < 4; ++r) {
          int row = w16 + quad*4 + r;
          bf16 vb = (bf16)acc[n][r];
          sqRo[row*S72 + col] = vb;
          tv[r] = vb;
        }
        *(bf16x4v*)(sqTo + col*S72 + w16 + quad*4) = tv;
      }
    }
    __syncthreads();
    bf16* prA = rc ? prod1 : prod0;
    bf16* prO = rc ? prod0 : prod1;
    {
      f32x4 acc[2];
      mm_band<2>(prA, sqTo, w16, chh*32, l16, quad, acc);
#pragma unroll
      for (int n = 0; n < 2; ++n) {
        int col = chh*32 + n*16 + l16;
        bf16x4v tv;
#pragma unroll
        for (int r = 0; r < 4; ++r) {
          int row = w16 + quad*4 + r;
          float val = acc[n][r] + (float)prA[row*S72 + col];
          prO[row*S72 + col] = (bf16)val;
          tv[r] = (bf16)(val * bts_s[col] * gms[col]);
        }
        if (i == 5) *(bf16x4v*)(T2T + col*S72 + w16 + quad*4) = tv;
      }
    }
    __syncthreads();
    pc ^= 1; rc ^= 1;
  }
  bf16* Mrow = rc ? prod1 : prod0;
  bf16* WR   = rc ? prod0 : prod1;

#pragma unroll
  for (int hf = 0; hf < 2; ++hf)
#pragma unroll
    for (int rr = 0; rr < 8; ++rr)
      VT[(hf*64 + lane)*S72 + (r0+rr)] = (bf16)(bts_s[r0+rr] * vreg[hf*8+rr]);
  __syncthreads();

  // V_loc^T
  {
    f32x4 acc[4];
    mm_band<4>(Mrow, VT, w16, chh*64, l16, quad, acc);
#pragma unroll
    for (int n = 0; n < 4; ++n) {
      int col = chh*64 + n*16 + l16;
      bf16x4v tv;
#pragma unroll
      for (int r = 0; r < 4; ++r) tv[r] = (bf16)acc[n][r];
      *(bf16x4v*)(VlT + col*S72 + w16 + quad*4) = tv;
    }
  }
  __syncthreads();

  // dS_loc
  {
    f32x4 acc[4];
    mm_band<4>(KbT, VlT, w16, chh*64, l16, quad, acc);
#pragma unroll
    for (int n = 0; n < 4; ++n) {
      int col = chh*64 + n*16 + l16;
#pragma unroll
      for (int r = 0; r < 4; ++r)
        dSl[(size_t)bx*8192 + (size_t)(w16 + quad*4 + r)*128 + col] = acc[n][r];
    }
  }
  // W2 = Kbar^T T2
  {
    f32x4 acc[2];
    mm_band<2>(KbT, T2T, w16, chh*32, l16, quad, acc);
#pragma unroll
    for (int n = 0; n < 2; ++n) {
      int col = chh*32 + n*16 + l16;
#pragma unroll
      for (int r = 0; r < 4; ++r)
        WR[(w16 + quad*4 + r)*S72 + col] = (bf16)acc[n][r];
    }
  }
  __syncthreads();
  // E -> EF planes 0/1 (hi/lo)
  {
    f32x4 acc[2];
    mm_band<2>(WR, KT, w16, chh*32, l16, quad, acc);
    float gC = gms[63];
    size_t eb = (size_t)bx * 13824;
#pragma unroll
    for (int n = 0; n < 2; ++n) {
      int col = chh*32 + n*16 + l16;
#pragma unroll
      for (int r = 0; r < 4; ++r) {
        int row = w16 + quad*4 + r;
        float ev = ((row == col) ? gC : 0.f) - acc[n][r];
        bf16 eh = (bf16)ev;
        EF[eb + row*S72 + col] = eh;
        EF[eb + 4608 + row*S72 + col] = (bf16)(ev - (float)eh);
      }
    }
  }
  __syncthreads();
  // R = P T2
  {
    f32x4 acc[2];
    mm_band<2>(Pm, T2T, w16, chh*32, l16, quad, acc);
#pragma unroll
    for (int n = 0; n < 2; ++n) {
      int col = chh*32 + n*16 + l16;
#pragma unroll
      for (int r = 0; r < 4; ++r)
        WR[(w16 + quad*4 + r)*S72 + col] = (bf16)acc[n][r];
    }
  }
  __syncthreads();
  // F -> EF plane 2
  {
    f32x4 acc[2];
    mm_band<2>(WR, KT, w16, chh*32, l16, quad, acc);
    size_t eb = (size_t)bx * 13824;
#pragma unroll
    for (int n = 0; n < 2; ++n) {
      int col = chh*32 + n*16 + l16;
#pragma unroll
      for (int r = 0; r < 4; ++r) {
        int row = w16 + quad*4 + r;
        float qv = qf[row*68 + col];
        EF[eb + 9216 + row*S72 + col] = (bf16)(gms[row]*qv - acc[n][r]);
      }
    }
  }
  // O_loc
  {
    f32x4 acc[4];
    mm_band<4>(Pm, VlT, w16, chh*64, l16, quad, acc);
#pragma unroll
    for (int n = 0; n < 4; ++n) {
      int col = chh*64 + n*16 + l16;
#pragma unroll
      for (int r = 0; r < 4; ++r)
        obuf[(size_t)(t0 + w16 + quad*4 + r)*2048 + h*128 + col] = acc[n][r];
    }
  }
}

// ---------------- MFMA sequential recurrence (round-5 structure) ----------------
// grid 64 = 16 heads x 4 dv-quarters (32 wide). 256 threads (4 waves, m-bands of 16).
__global__ __launch_bounds__(256) void k_seq(const bf16* __restrict__ EF,
    const float* __restrict__ dSl, float* __restrict__ osb) {
  const int h = blockIdx.x >> 2, dq = blockIdx.x & 3;
  const int tid = threadIdx.x, wave = tid >> 6, lane = tid & 63;
  const int l16 = lane & 15, quad = lane >> 4;
  const int mb = wave * 16;
  __shared__ bf16 ebuf[2][13824];
  __shared__ bf16 Sthi[32*S72], Stlo[32*S72];
  for (int i = tid; i < 2304; i += 256) { Sthi[i] = (bf16)0.f; Stlo[i] = (bf16)0.f; }
  {
    const bf16* efg = EF + (size_t)h * 13824;
    for (int i = tid; i < 1728; i += 256)
      __builtin_amdgcn_global_load_lds(
        (__attribute__((address_space(1))) void*)(efg + i*8),
        (__attribute__((address_space(3))) void*)(&ebuf[0][i*8]), 16, 0, 0);
  }
  float dsv[8];
  {
    size_t base = (size_t)h*8192 + dq*32;
#pragma unroll
    for (int nt = 0; nt < 2; ++nt)
#pragma unroll
      for (int r = 0; r < 4; ++r)
        dsv[nt*4+r] = dSl[base + (size_t)(mb + quad*4 + r)*128 + nt*16 + l16];
  }
  __syncthreads();
#pragma unroll 1
  for (int c = 0; c < 32; ++c) {
    const int cur = c & 1, nxt = cur ^ 1;
    float dsn[8] = {};
    if (c + 1 < 32) {
      const bf16* efg = EF + (size_t)((c+1)*16 + h) * 13824;
      for (int i = tid; i < 1728; i += 256)
        __builtin_amdgcn_global_load_lds(
          (__attribute__((address_space(1))) void*)(efg + i*8),
          (__attribute__((address_space(3))) void*)(&ebuf[nxt][i*8]), 16, 0, 0);
      size_t base = (size_t)((c+1)*16 + h)*8192 + dq*32;
#pragma unroll
      for (int nt = 0; nt < 2; ++nt)
#pragma unroll
        for (int r = 0; r < 4; ++r)
          dsn[nt*4+r] = dSl[base + (size_t)(mb + quad*4 + r)*128 + nt*16 + l16];
    }
    const bf16* Eh = &ebuf[cur][0];
    const bf16* El = &ebuf[cur][4608];
    const bf16* Ff = &ebuf[cur][9216];
    bf16x8 bh[2][2], bl[2][2];
#pragma unroll
    for (int nt = 0; nt < 2; ++nt)
#pragma unroll
      for (int kt = 0; kt < 2; ++kt) {
        bh[nt][kt] = *(const bf16x8*)(Sthi + (nt*16 + l16)*S72 + kt*32 + quad*8);
        bl[nt][kt] = *(const bf16x8*)(Stlo + (nt*16 + l16)*S72 + kt*32 + quad*8);
      }
    f32x4 accS[2], accO[2];
#pragma unroll
    for (int nt = 0; nt < 2; ++nt) {
#pragma unroll
      for (int r = 0; r < 4; ++r) accS[nt][r] = dsv[nt*4+r];
      accO[nt][0]=0.f; accO[nt][1]=0.f; accO[nt][2]=0.f; accO[nt][3]=0.f;
    }
#pragma unroll
    for (int kt = 0; kt < 2; ++kt) {
      bf16x8 aeh = *(const bf16x8*)(Eh + (mb + l16)*S72 + kt*32 + quad*8);
      bf16x8 ael = *(const bf16x8*)(El + (mb + l16)*S72 + kt*32 + quad*8);
      bf16x8 aff = *(const bf16x8*)(Ff + (mb + l16)*S72 + kt*32 + quad*8);
#pragma unroll
      for (int nt = 0; nt < 2; ++nt) {
        accS[nt] = __builtin_amdgcn_mfma_f32_16x16x32_bf16(aeh, bh[nt][kt], accS[nt], 0, 0, 0);
        accS[nt] = __builtin_amdgcn_mfma_f32_16x16x32_bf16(aeh, bl[nt][kt], accS[nt], 0, 0, 0);
        accS[nt] = __builtin_amdgcn_mfma_f32_16x16x32_bf16(ael, bh[nt][kt], accS[nt], 0, 0, 0);
        accO[nt] = __builtin_amdgcn_mfma_f32_16x16x32_bf16(aff, bh[nt][kt], accO[nt], 0, 0, 0);
        accO[nt] = __builtin_amdgcn_mfma_f32_16x16x32_bf16(aff, bl[nt][kt], accO[nt], 0, 0, 0);
      }
    }
    __syncthreads();
    {
      int t0 = c*64;
#pragma unroll
      for (int nt = 0; nt < 2; ++nt)
#pragma unroll
        for (int r = 0; r < 4; ++r)
          osb[(size_t)(t0 + mb + quad*4 + r)*2048 + h*128 + dq*32 + nt*16 + l16] = accO[nt][r];
    }
#pragma unroll
    for (int nt = 0; nt < 2; ++nt) {
      bf16x4v hv, lv;
#pragma unroll
      for (int r = 0; r < 4; ++r) {
        float v = accS[nt][r];
        bf16 hb = (bf16)v;
        hv[r] = hb;
        lv[r] = (bf16)(v - (float)hb);
      }
      *(bf16x4v*)(Sthi + (nt*16 + l16)*S72 + mb + quad*4) = hv;
      *(bf16x4v*)(Stlo + (nt*16 + l16)*S72 + mb + quad*4) = lv;
    }
#pragma unroll
    for (int i = 0; i < 8; ++i) dsv[i] = dsn[i];
    __syncthreads();
  }
}

// ---------------- gated RMSNorm on o = O_loc + O_s, write bf16 ----------------
__global__ __launch_bounds__(64) void k_gatenorm(const float* __restrict__ o,
    const float* __restrict__ os, const bf16* __restrict__ gpre,
    const float* __restrict__ onw, bf16* __restrict__ og) {
  int t = blockIdx.x, hh = blockIdx.y, lane = threadIdx.x;
  size_t base = (size_t)t*2048 + hh*128 + lane*2;
  float2 o2 = *(const float2*)(o + base);
  float2 s2 = *(const float2*)(os + base);
  o2.x += s2.x; o2.y += s2.y;
  float ss = wredsum(o2.x*o2.x + o2.y*o2.y);
  float rs = rsqrtf(ss * (1.f/128.f) + 1e-5f);
  float2 nw = *(const float2*)(onw + lane*2);
  bf16x2v g2 = *(const bf16x2v*)(gpre + base);
  float g0 = (float)g2[0], g1 = (float)g2[1];
  float r0 = o2.x * rs * nw.x * (g0 * sigmoidf_(g0));
  float r1 = o2.y * rs * nw.y * (g1 * sigmoidf_(g1));
  bf16x2v b; b[0] = (bf16)r0; b[1] = (bf16)r1;
  *(bf16x2v*)(og + base) = b;
}

extern "C" void kernel_launch(void* const* d_in, const int* in_sizes, int n_in,
                              void* d_out, int out_size, void* d_ws, size_t ws_size,
                              hipStream_t stream) {
  const float* hs   = (const float*)d_in[0];
  const float* nw   = (const float*)d_in[1];
  const float* qw   = (const float*)d_in[2];
  const float* kw   = (const float*)d_in[3];
  const float* vw   = (const float*)d_in[4];
  const float* aw   = (const float*)d_in[5];
  const float* bw   = (const float*)d_in[6];
  const float* gw   = (const float*)d_in[7];
  const float* dtb  = (const float*)d_in[8];
  const float* alog = (const float*)d_in[9];
  const float* cqw  = (const float*)d_in[10];
  const float* ckw  = (const float*)d_in[11];
  const float* cvw  = (const float*)d_in[12];
  const float* onw  = (const float*)d_in[13];
  const float* opw  = (const float*)d_in[14];
  const float* ow   = (const float*)d_in[15];
  float* out = (float*)d_out;

  char* p = (char*)d_ws;
  auto alloc = [&](size_t bytes) { char* r = p; p += (bytes + 255) & ~255ull; return r; };
  bf16*  xb    = (bf16*) alloc((size_t)2048*1024*2);   // } dSl aliases xb..gwb (16 MB,
  bf16*  qwb   = (bf16*) alloc((size_t)1024*1024*2);   // } all dead after k_gemm_proj)
  bf16*  kwb   = (bf16*) alloc((size_t)1024*1024*2);
  bf16*  vwb   = (bf16*) alloc((size_t)2048*1024*2);
  bf16*  gwb   = (bf16*) alloc((size_t)2048*1024*2);
  bf16*  opwb  = (bf16*) alloc((size_t)1024*2048*2);
  bf16*  owb   = (bf16*) alloc((size_t)1024*1024*2);
  bf16*  qpre  = (bf16*) alloc((size_t)2048*1024*2);
  bf16*  kpre  = (bf16*) alloc((size_t)2048*1024*2);
  bf16*  vpre  = (bf16*) alloc((size_t)2048*2048*2);
  bf16*  gpre  = (bf16*) alloc((size_t)2048*2048*2);
  float* graw  = (float*)alloc((size_t)2048*16*4);
  float* btb   = (float*)alloc((size_t)2048*16*4);
  float* ob    = (float*)alloc((size_t)2048*2048*4);
  bf16*  ogb   = (bf16*) alloc((size_t)2048*2048*2);
  bf16*  h1b   = (bf16*) alloc((size_t)2048*1024*2);
  bf16*  EF    = (bf16*) alloc((size_t)512*13824*2);
  float* osb   = (float*)alloc((size_t)512*8192*4);
  float* dSl   = (float*)xb;   // 16 MB over xb..gwb (dead after k_gemm_proj)

  k_rmsnorm<<<2048, 256, 0, stream>>>(hs, nw, aw, bw, dtb, alog, xb, graw, btb);
  k_castw<<<4608, 256, 0, stream>>>(qw, kw, vw, gw, opw, ow, qwb, kwb, vwb, gwb, opwb, owb);
  k_gemm_proj<<<dim3(48,16,1), 256, 0, stream>>>(xb, qwb, kwb, vwb, gwb, qpre, kpre, vpre, gpre);
  k_prepass<<<512, 512, 0, stream>>>(qpre, kpre, vpre, cqw, ckw, cvw, graw, btb, EF, dSl, ob);
  k_seq<<<64, 256, 0, stream>>>(EF, dSl, osb);
  k_gatenorm<<<dim3(2048,16,1), 64, 0, stream>>>(ob, osb, gpre, onw, ogb);
  k_gemm_bt<bf16><<<dim3(8,16,1), 256, 0, stream>>>(ogb, opwb, h1b, 1024, 2048);
  k_gemm_bt<float><<<dim3(8,16,1), 256, 0, stream>>>(h1b, owb, out, 1024, 1024);
}

// Round 8
// 286.160 us; speedup vs baseline: 1.3015x; 1.0899x over previous
//
#include <hip/hip_runtime.h>
#include <math.h>

#define S72 72

typedef __bf16 bf16;
typedef __bf16 bf16x8 __attribute__((ext_vector_type(8)));
typedef __bf16 bf16x4v __attribute__((ext_vector_type(4)));
typedef __bf16 bf16x2v __attribute__((ext_vector_type(2)));
typedef float f32x4 __attribute__((ext_vector_type(4)));

__device__ __forceinline__ float wredsum(float v) {
#pragma unroll
  for (int off = 32; off > 0; off >>= 1) v += __shfl_xor(v, off, 64);
  return v;
}
__device__ __forceinline__ float sigmoidf_(float x) { return 1.f / (1.f + __expf(-x)); }

// swizzled LDS addressing for 64-col planes: row stride 64, 8-elem chunks XOR'd by row&7
__device__ __forceinline__ int sxy(int row, int col) {
  return (row << 6) + ((((col >> 3) ^ (row & 7)) << 3) | (col & 7));
}
__device__ __forceinline__ int sx8(int row, int chunk) {
  return (row << 6) + ((chunk ^ (row & 7)) << 3);
}

// ---------------- fused: RMSNorm + a/b projections  |  weight cast ----------------
__global__ __launch_bounds__(256) void k_pre(const float* __restrict__ h,
    const float* __restrict__ nw, const float* __restrict__ aw,
    const float* __restrict__ bw, const float* __restrict__ dtb,
    const float* __restrict__ alog, bf16* __restrict__ xb,
    float* __restrict__ graw, float* __restrict__ btb,
    const float* __restrict__ qw, const float* __restrict__ kw,
    const float* __restrict__ vw, const float* __restrict__ gw,
    const float* __restrict__ opw, const float* __restrict__ ow,
    bf16* qwb, bf16* kwb, bf16* vwb, bf16* gwb, bf16* opwb, bf16* owb) {
  __shared__ float red[4];
  __shared__ __align__(16) float xs[1024];
  int tid = threadIdx.x;
  if (blockIdx.x >= 2048) {
    // weight cast part (4608 virtual blocks)
    long cb = blockIdx.x - 2048;
    for (long u = cb*256 + tid; u < 2359296; u += 4608l*256) {
      const float* src; bf16* dst; long l;
      if      (u <  262144) { src=qw;  dst=qwb;  l=u; }
      else if (u <  524288) { src=kw;  dst=kwb;  l=u-262144; }
      else if (u < 1048576) { src=vw;  dst=vwb;  l=u-524288; }
      else if (u < 1572864) { src=gw;  dst=gwb;  l=u-1048576; }
      else if (u < 2097152) { src=opw; dst=opwb; l=u-1572864; }
      else                  { src=ow;  dst=owb;  l=u-2097152; }
      float4 s = *(const float4*)(src + l*4);
      bf16x4v b; b[0]=(bf16)s.x; b[1]=(bf16)s.y; b[2]=(bf16)s.z; b[3]=(bf16)s.w;
      *(bf16x4v*)(dst + l*4) = b;
    }
    return;
  }
  int t = blockIdx.x;
  float4 hv = *(const float4*)(h + (size_t)t*1024 + tid*4);
  float ss = hv.x*hv.x + hv.y*hv.y + hv.z*hv.z + hv.w*hv.w;
  float wsum = wredsum(ss);
  if ((tid & 63) == 0) red[tid >> 6] = wsum;
  __syncthreads();
  float tot = red[0] + red[1] + red[2] + red[3];
  float rs = rsqrtf(tot * (1.f/1024.f) + 1e-6f);
  float4 w4 = *(const float4*)(nw + tid*4);
  float4 y;
  y.x = hv.x*rs*w4.x; y.y = hv.y*rs*w4.y; y.z = hv.z*rs*w4.z; y.w = hv.w*rs*w4.w;
  *(float4*)(xs + tid*4) = y;
  bf16x4v b; b[0]=(bf16)y.x; b[1]=(bf16)y.y; b[2]=(bf16)y.z; b[3]=(bf16)y.w;
  *(bf16x4v*)(xb + (size_t)t*1024 + tid*4) = b;
  __syncthreads();
  int wave = tid >> 6, lane = tid & 63;
  const float4* x4 = (const float4*)xs;
#pragma unroll
  for (int hi = 0; hi < 4; ++hi) {
    int hh = wave*4 + hi;
    float sa = 0.f, sb = 0.f;
#pragma unroll
    for (int i = 0; i < 4; ++i) {
      float4 xv = x4[i*64 + lane];
      float4 av = *(const float4*)(aw + hh*1024 + i*256 + lane*4);
      float4 bv = *(const float4*)(bw + hh*1024 + i*256 + lane*4);
      sa += xv.x*av.x + xv.y*av.y + xv.z*av.z + xv.w*av.w;
      sb += xv.x*bv.x + xv.y*bv.y + xv.z*bv.z + xv.w*bv.w;
    }
    sa = wredsum(sa); sb = wredsum(sb);
    if (lane == 0) {
      float ap = sa + dtb[hh];
      float sp = (ap > 20.f) ? ap : log1pf(expf(ap));
      graw[t*16 + hh] = -expf(alog[hh]) * sp;
      btb[t*16 + hh] = 1.f / (1.f + expf(-sb));
    }
  }
}

// ---------------- bf16 MFMA GEMM 128x128 (double-buffered, XOR-swizzled) ----------------
template <typename OutT>
__device__ __forceinline__ void gemm_body(const bf16* __restrict__ A,
    const bf16* __restrict__ B, OutT* __restrict__ C, int N, int K, int m0, int n0) {
  __shared__ bf16 As[2][128*32];
  __shared__ bf16 Bs[2][128*32];
  const int tid = threadIdx.x, lane = tid & 63, wave = tid >> 6;
  const int wm = (wave >> 1) * 64, wn = (wave & 1) * 64;
  const int srow = wave*16 + (lane >> 2);
  const int swl = (((lane & 3) ^ ((lane >> 3) & 3))) * 8;
  const int sdst = (lane & 3) * 8;
  const int quad = lane >> 4, l16 = lane & 15;
  const int sw = (l16 >> 1) & 3;
  f32x4 acc[4][4] = {};
  const int nk = K >> 5;
#pragma unroll
  for (int i = 0; i < 2; ++i) {
    int r = i*64 + srow;
    __builtin_amdgcn_global_load_lds(
      (__attribute__((address_space(1))) void*)(A + (size_t)(m0 + r)*K + swl),
      (__attribute__((address_space(3))) void*)(&As[0][r*32 + sdst]), 16, 0, 0);
    __builtin_amdgcn_global_load_lds(
      (__attribute__((address_space(1))) void*)(B + (size_t)(n0 + r)*K + swl),
      (__attribute__((address_space(3))) void*)(&Bs[0][r*32 + sdst]), 16, 0, 0);
  }
  for (int kt = 0; kt < nk; ++kt) {
    const int cur = kt & 1;
    __syncthreads();
    bf16x8 af[4], bfr[4];
#pragma unroll
    for (int mt = 0; mt < 4; ++mt)
      af[mt] = *(const bf16x8*)(&As[cur][(wm + mt*16 + l16)*32 + (quad ^ sw)*8]);
#pragma unroll
    for (int nt = 0; nt < 4; ++nt)
      bfr[nt] = *(const bf16x8*)(&Bs[cur][(wn + nt*16 + l16)*32 + (quad ^ sw)*8]);
    if (kt + 1 < nk) {
      int k0 = (kt + 1) << 5;
#pragma unroll
      for (int i = 0; i < 2; ++i) {
        int r = i*64 + srow;
        __builtin_amdgcn_global_load_lds(
          (__attribute__((address_space(1))) void*)(A + (size_t)(m0 + r)*K + k0 + swl),
          (__attribute__((address_space(3))) void*)(&As[cur^1][r*32 + sdst]), 16, 0, 0);
        __builtin_amdgcn_global_load_lds(
          (__attribute__((address_space(1))) void*)(B + (size_t)(n0 + r)*K + k0 + swl),
          (__attribute__((address_space(3))) void*)(&Bs[cur^1][r*32 + sdst]), 16, 0, 0);
      }
    }
#pragma unroll
    for (int mt = 0; mt < 4; ++mt)
#pragma unroll
      for (int nt = 0; nt < 4; ++nt)
        acc[mt][nt] = __builtin_amdgcn_mfma_f32_16x16x32_bf16(af[mt], bfr[nt], acc[mt][nt], 0, 0, 0);
  }
#pragma unroll
  for (int mt = 0; mt < 4; ++mt)
#pragma unroll
    for (int nt = 0; nt < 4; ++nt)
#pragma unroll
      for (int r = 0; r < 4; ++r) {
        int row = m0 + wm + mt*16 + quad*4 + r;
        int col = n0 + wn + nt*16 + l16;
        C[(size_t)row*N + col] = (OutT)acc[mt][nt][r];
      }
}

__global__ __launch_bounds__(256) void k_gemm_proj(const bf16* __restrict__ A,
    const bf16* __restrict__ qwb, const bf16* __restrict__ kwb,
    const bf16* __restrict__ vwb, const bf16* __restrict__ gwb,
    bf16* __restrict__ qpre, bf16* __restrict__ kpre,
    bf16* __restrict__ vpre, bf16* __restrict__ gpre) {
  int bx = blockIdx.x;
  const bf16* B; bf16* C; int N, xt;
  if      (bx <  8) { B = qwb; C = qpre; N = 1024; xt = bx; }
  else if (bx < 16) { B = kwb; C = kpre; N = 1024; xt = bx - 8; }
  else if (bx < 32) { B = vwb; C = vpre; N = 2048; xt = bx - 16; }
  else              { B = gwb; C = gpre; N = 2048; xt = bx - 32; }
  gemm_body<bf16>(A, B, C, N, 1024, blockIdx.y*128, xt*128);
}

// ---------------- bf16 MFMA GEMM 128x64 (2x blocks for tail GEMMs) ----------------
template <typename OutT>
__global__ __launch_bounds__(256) void k_gemm_bt64(const bf16* __restrict__ A,
    const bf16* __restrict__ B, OutT* __restrict__ C, int N, int K) {
  __shared__ bf16 As[2][128*32];
  __shared__ bf16 Bs[2][64*32];
  const int tid = threadIdx.x, lane = tid & 63, wave = tid >> 6;
  const int wm = wave * 32;
  const int srow = wave*16 + (lane >> 2);
  const int swl = (((lane & 3) ^ ((lane >> 3) & 3))) * 8;
  const int sdst = (lane & 3) * 8;
  const int quad = lane >> 4, l16 = lane & 15;
  const int sw = (l16 >> 1) & 3;
  const int m0 = blockIdx.y * 128, n0 = blockIdx.x * 64;
  f32x4 acc[2][4] = {};
  const int nk = K >> 5;
#pragma unroll
  for (int i = 0; i < 2; ++i) {
    int r = i*64 + srow;
    __builtin_amdgcn_global_load_lds(
      (__attribute__((address_space(1))) void*)(A + (size_t)(m0 + r)*K + swl),
      (__attribute__((address_space(3))) void*)(&As[0][r*32 + sdst]), 16, 0, 0);
  }
  __builtin_amdgcn_global_load_lds(
    (__attribute__((address_space(1))) void*)(B + (size_t)(n0 + srow)*K + swl),
    (__attribute__((address_space(3))) void*)(&Bs[0][srow*32 + sdst]), 16, 0, 0);
  for (int kt = 0; kt < nk; ++kt) {
    const int cur = kt & 1;
    __syncthreads();
    bf16x8 af[2], bfr[4];
#pragma unroll
    for (int mt = 0; mt < 2; ++mt)
      af[mt] = *(const bf16x8*)(&As[cur][(wm + mt*16 + l16)*32 + (quad ^ sw)*8]);
#pragma unroll
    for (int nt = 0; nt < 4; ++nt)
      bfr[nt] = *(const bf16x8*)(&Bs[cur][(nt*16 + l16)*32 + (quad ^ sw)*8]);
    if (kt + 1 < nk) {
      int k0 = (kt + 1) << 5;
#pragma unroll
      for (int i = 0; i < 2; ++i) {
        int r = i*64 + srow;
        __builtin_amdgcn_global_load_lds(
          (__attribute__((address_space(1))) void*)(A + (size_t)(m0 + r)*K + k0 + swl),
          (__attribute__((address_space(3))) void*)(&As[cur^1][r*32 + sdst]), 16, 0, 0);
      }
      __builtin_amdgcn_global_load_lds(
        (__attribute__((address_space(1))) void*)(B + (size_t)(n0 + srow)*K + k0 + swl),
        (__attribute__((address_space(3))) void*)(&Bs[cur^1][srow*32 + sdst]), 16, 0, 0);
    }
#pragma unroll
    for (int mt = 0; mt < 2; ++mt)
#pragma unroll
      for (int nt = 0; nt < 4; ++nt)
        acc[mt][nt] = __builtin_amdgcn_mfma_f32_16x16x32_bf16(af[mt], bfr[nt], acc[mt][nt], 0, 0, 0);
  }
#pragma unroll
  for (int mt = 0; mt < 2; ++mt)
#pragma unroll
    for (int nt = 0; nt < 4; ++nt)
#pragma unroll
      for (int r = 0; r < 4; ++r) {
        int row = m0 + wm + mt*16 + quad*4 + r;
        int col = n0 + nt*16 + l16;
        C[(size_t)row*N + col] = (OutT)acc[mt][nt][r];
      }
}

// ---------------- MFMA chunked delta-rule pre-pass (conv fused, 2 blocks/CU) ----------------
// 8 stride-64 XOR-swizzled planes + q plane = 73 KB LDS. Plane life-cycle:
//  A:Kr->VT(lo) B:powR0->VT(hi) C:prod0->WR->VlT(lo) D:T2T->VlT(hi)
//  E:powT0->KT  F:powR1->KbT    G:powT1->Pm          H:prod1(Mrow)  Q:qbf
template<int NT>
__device__ __forceinline__ void mm_band(const bf16* A_lds, const bf16* B_lds,
    int w16, int cb, int l16, int quad, f32x4* acc) {
#pragma unroll
  for (int n = 0; n < NT; ++n) { acc[n][0]=0.f; acc[n][1]=0.f; acc[n][2]=0.f; acc[n][3]=0.f; }
#pragma unroll
  for (int kt = 0; kt < 2; ++kt) {
    bf16x8 af = *(const bf16x8*)(A_lds + sx8(w16 + l16, kt*4 + quad));
#pragma unroll
    for (int n = 0; n < NT; ++n) {
      bf16x8 bf = *(const bf16x8*)(B_lds + sx8(cb + n*16 + l16, kt*4 + quad));
      acc[n] = __builtin_amdgcn_mfma_f32_16x16x32_bf16(af, bf, acc[n], 0, 0, 0);
    }
  }
}

__global__ __launch_bounds__(512) void k_prepass(
    const bf16* __restrict__ qpre, const bf16* __restrict__ kpre,
    const bf16* __restrict__ vpre, const float* __restrict__ cqw,
    const float* __restrict__ ckw, const float* __restrict__ cvw,
    const float* __restrict__ graw, const float* __restrict__ beta,
    bf16* __restrict__ EF, float* __restrict__ dSl, float* __restrict__ obuf) {
  const int bx = blockIdx.x, c = bx >> 4, h = bx & 15, tid = threadIdx.x;
  const int t0 = c * 64;
  const int wave = tid >> 6, lane = tid & 63, l16 = lane & 15, quad = lane >> 4;
  const int w16 = (wave >> 1) * 16;
  const int chh = wave & 1;
  const int r0 = wave * 8;

  __shared__ bf16 SM[36864];
  __shared__ float bs[64], bts_s[64], es[64], gms[64];
  bf16* Kr    = SM;            // A
  bf16* powR0 = SM + 4096;     // B
  bf16* prod0 = SM + 8192;     // C
  bf16* T2T   = SM + 12288;    // D
  bf16* powT0 = SM + 16384;    // E
  bf16* powR1 = SM + 20480;    // F
  bf16* powT1 = SM + 24576;    // G
  bf16* prod1 = SM + 28672;    // H
  bf16* qbf   = SM + 32768;    // Q
  bf16* VT   = SM;             // rows 0..127 over A+B
  bf16* VlT  = SM + 8192;      // rows 0..127 over C+D
  bf16* KT   = powT0;
  bf16* KbT  = powR1;
  bf16* Pm   = powT1;
  bf16* WR   = prod0;
  bf16* Mrow = prod1;

  if (tid < 64) {
    float g = graw[(size_t)(t0 + tid)*16 + h];
    float b = g;
#pragma unroll
    for (int off = 1; off < 64; off <<= 1) {
      float p = __shfl_up(b, off, 64);
      if (tid >= off) b += p;
    }
    bs[tid] = b;
    bts_s[tid] = beta[(size_t)(t0 + tid)*16 + h];
    float b63 = __shfl(b, 63, 64);
    es[tid] = __expf(b63 - b);
    gms[tid] = __expf(b);
  }

  // fused conv(K=4)+silu+norms; wave owns rows r0..r0+7, channel = lane
  float kreg[8], vreg[16];
  {
    float4 wq  = *(const float4*)(cqw + (h*64 + lane)*4);
    float4 wk  = *(const float4*)(ckw + (h*64 + lane)*4);
    float tv[11];
#pragma unroll
    for (int j = 0; j < 11; ++j) {
      int tg = t0 + r0 + j - 3;
      tv[j] = (tg >= 0) ? (float)qpre[(size_t)tg*1024 + h*64 + lane] : 0.f;
    }
#pragma unroll
    for (int rr = 0; rr < 8; ++rr) {
      float y = tv[rr]*wq.x + tv[rr+1]*wq.y + tv[rr+2]*wq.z + tv[rr+3]*wq.w;
      y = y * sigmoidf_(y);
      float ssq = wredsum(y*y);
      y *= rsqrtf(ssq + 1e-6f) * 0.125f;
      qbf[sxy(r0+rr, lane)] = (bf16)y;
    }
#pragma unroll
    for (int j = 0; j < 11; ++j) {
      int tg = t0 + r0 + j - 3;
      tv[j] = (tg >= 0) ? (float)kpre[(size_t)tg*1024 + h*64 + lane] : 0.f;
    }
#pragma unroll
    for (int rr = 0; rr < 8; ++rr) {
      float y = tv[rr]*wk.x + tv[rr+1]*wk.y + tv[rr+2]*wk.z + tv[rr+3]*wk.w;
      y = y * sigmoidf_(y);
      float m = wredsum(y) * (1.f/64.f);
      y -= m;
      float ssq = wredsum(y*y);
      y *= rsqrtf(ssq + 1e-6f);
      kreg[rr] = y;
      Kr[sxy(r0+rr, lane)] = (bf16)y;
    }
#pragma unroll
    for (int hf = 0; hf < 2; ++hf) {
      float4 wv = *(const float4*)(cvw + (h*128 + hf*64 + lane)*4);
#pragma unroll
      for (int j = 0; j < 11; ++j) {
        int tg = t0 + r0 + j - 3;
        tv[j] = (tg >= 0) ? (float)vpre[(size_t)tg*2048 + h*128 + hf*64 + lane] : 0.f;
      }
#pragma unroll
      for (int rr = 0; rr < 8; ++rr) {
        float y = tv[rr]*wv.x + tv[rr+1]*wv.y + tv[rr+2]*wv.z + tv[rr+3]*wv.w;
        vreg[hf*8+rr] = y * sigmoidf_(y);
      }
    }
  }
  __syncthreads();

  // A-build: N = -A from K K^T; prod0 = I + N
  {
    f32x4 acc[2];
    mm_band<2>(Kr, Kr, w16, chh*32, l16, quad, acc);
#pragma unroll
    for (int n = 0; n < 2; ++n) {
      int col = chh*32 + n*16 + l16;
      bf16x4v tv;
#pragma unroll
      for (int r = 0; r < 4; ++r) {
        int row = w16 + quad*4 + r;
        float nv = 0.f;
        if (row > col) nv = -bts_s[row] * __expf(bs[row] - bs[col]) * acc[n][r];
        bf16 nb = (bf16)nv;
        powR0[sxy(row, col)] = nb;
        tv[r] = nb;
        prod0[sxy(row, col)] = (row == col) ? (bf16)1.f : nb;
      }
      *(bf16x4v*)(powT0 + sxy(col, w16 + quad*4)) = tv;
    }
  }
  __syncthreads();

  // squaring chain: (I+A)^-1 = prod (I + N^(2^i))
  int pc = 0, rc = 0;
#pragma unroll 1
  for (int i = 1; i <= 5; ++i) {
    bf16* sqA = pc ? powR1 : powR0;
    bf16* sqB = pc ? powT1 : powT0;
    bf16* sqRo = pc ? powR0 : powR1;
    bf16* sqTo = pc ? powT0 : powT1;
    {
      f32x4 acc[2];
      mm_band<2>(sqA, sqB, w16, chh*32, l16, quad, acc);
#pragma unroll
      for (int n = 0; n < 2; ++n) {
        int col = chh*32 + n*16 + l16;
        bf16x4v tv;
#pragma unroll
        for (int r = 0; r < 4; ++r) {
          int row = w16 + quad*4 + r;
          bf16 vb = (bf16)acc[n][r];
          sqRo[sxy(row, col)] = vb;
          tv[r] = vb;
        }
        *(bf16x4v*)(sqTo + sxy(col, w16 + quad*4)) = tv;
      }
    }
    __syncthreads();
    bf16* prA = rc ? prod1 : prod0;
    bf16* prO = rc ? prod0 : prod1;
    {
      f32x4 acc[2];
      mm_band<2>(prA, sqTo, w16, chh*32, l16, quad, acc);
#pragma unroll
      for (int n = 0; n < 2; ++n) {
        int col = chh*32 + n*16 + l16;
        bf16x4v tv;
#pragma unroll
        for (int r = 0; r < 4; ++r) {
          int row = w16 + quad*4 + r;
          float val = acc[n][r] + (float)prA[sxy(row, col)];
          prO[sxy(row, col)] = (bf16)val;
          tv[r] = (bf16)(val * bts_s[col] * gms[col]);
        }
        if (i == 5) *(bf16x4v*)(T2T + sxy(col, w16 + quad*4)) = tv;
      }
    }
    __syncthreads();
    pc ^= 1; rc ^= 1;
  }
  // after chain: Mrow = prod1, pow planes dead

  // KT/KbT from registers; Pm build (reads Kr + qbf)
#pragma unroll
  for (int rr = 0; rr < 8; ++rr) {
    KT[sxy(lane, r0+rr)]  = (bf16)kreg[rr];
    KbT[sxy(lane, r0+rr)] = (bf16)(kreg[rr] * es[r0+rr]);
  }
  {
    f32x4 acc[2];
#pragma unroll
    for (int n = 0; n < 2; ++n) { acc[n][0]=0.f; acc[n][1]=0.f; acc[n][2]=0.f; acc[n][3]=0.f; }
#pragma unroll
    for (int kt = 0; kt < 2; ++kt) {
      bf16x8 af = *(const bf16x8*)(qbf + sx8(w16 + l16, kt*4 + quad));
#pragma unroll
      for (int n = 0; n < 2; ++n) {
        bf16x8 bf = *(const bf16x8*)(Kr + sx8(chh*32 + n*16 + l16, kt*4 + quad));
        acc[n] = __builtin_amdgcn_mfma_f32_16x16x32_bf16(af, bf, acc[n], 0, 0, 0);
      }
    }
#pragma unroll
    for (int n = 0; n < 2; ++n) {
      int col = chh*32 + n*16 + l16;
#pragma unroll
      for (int r = 0; r < 4; ++r) {
        int row = w16 + quad*4 + r;
        float pv = (row >= col) ? __expf(bs[row] - bs[col]) * acc[n][r] : 0.f;
        Pm[sxy(row, col)] = (bf16)pv;
      }
    }
  }
  __syncthreads();

  // W2 = Kbar^T T2 -> WR ; VT from vreg (Kr/powR0 dead)
  {
    f32x4 acc[2];
    mm_band<2>(KbT, T2T, w16, chh*32, l16, quad, acc);
#pragma unroll
    for (int n = 0; n < 2; ++n) {
      int col = chh*32 + n*16 + l16;
#pragma unroll
      for (int r = 0; r < 4; ++r)
        WR[sxy(w16 + quad*4 + r, col)] = (bf16)acc[n][r];
    }
  }
#pragma unroll
  for (int hf = 0; hf < 2; ++hf)
#pragma unroll
    for (int rr = 0; rr < 8; ++rr)
      VT[sxy(hf*64 + lane, r0+rr)] = (bf16)(bts_s[r0+rr] * vreg[hf*8+rr]);
  __syncthreads();
  // E = gamma_C I - W2 K -> EF planes 0/1 (hi/lo)
  {
    f32x4 acc[2];
    mm_band<2>(WR, KT, w16, chh*32, l16, quad, acc);
    float gC = gms[63];
    size_t eb = (size_t)bx * 13824;
#pragma unroll
    for (int n = 0; n < 2; ++n) {
      int col = chh*32 + n*16 + l16;
#pragma unroll
      for (int r = 0; r < 4; ++r) {
        int row = w16 + quad*4 + r;
        float ev = ((row == col) ? gC : 0.f) - acc[n][r];
        bf16 eh = (bf16)ev;
        EF[eb + row*S72 + col] = eh;
        EF[eb + 4608 + row*S72 + col] = (bf16)(ev - (float)eh);
      }
    }
  }
  __syncthreads();
  // R = P T2 -> WR
  {
    f32x4 acc[2];
    mm_band<2>(Pm, T2T, w16, chh*32, l16, quad, acc);
#pragma unroll
    for (int n = 0; n < 2; ++n) {
      int col = chh*32 + n*16 + l16;
#pragma unroll
      for (int r = 0; r < 4; ++r)
        WR[sxy(w16 + quad*4 + r, col)] = (bf16)acc[n][r];
    }
  }
  __syncthreads();
  // F = diag(gamma) Q - R K -> EF plane 2
  {
    f32x4 acc[2];
    mm_band<2>(WR, KT, w16, chh*32, l16, quad, acc);
    size_t eb = (size_t)bx * 13824;
#pragma unroll
    for (int n = 0; n < 2; ++n) {
      int col = chh*32 + n*16 + l16;
#pragma unroll
      for (int r = 0; r < 4; ++r) {
        int row = w16 + quad*4 + r;
        float qv = (float)qbf[sxy(row, col)];
        EF[eb + 9216 + row*S72 + col] = (bf16)(gms[row]*qv - acc[n][r]);
      }
    }
  }
  __syncthreads();   // WR/T2T reads done before VlT overwrites C+D
  // V_loc = M (beta V): write V_loc^T into VlT
  {
    f32x4 acc[4];
    mm_band<4>(Mrow, VT, w16, chh*64, l16, quad, acc);
#pragma unroll
    for (int n = 0; n < 4; ++n) {
      int col = chh*64 + n*16 + l16;
      bf16x4v tv;
#pragma unroll
      for (int r = 0; r < 4; ++r) tv[r] = (bf16)acc[n][r];
      *(bf16x4v*)(VlT + sxy(col, w16 + quad*4)) = tv;
    }
  }
  __syncthreads();
  // dS_loc = Kbar^T V_loc ; O_loc = P V_loc
  {
    f32x4 acc[4];
    mm_band<4>(KbT, VlT, w16, chh*64, l16, quad, acc);
#pragma unroll
    for (int n = 0; n < 4; ++n) {
      int col = chh*64 + n*16 + l16;
#pragma unroll
      for (int r = 0; r < 4; ++r)
        dSl[(size_t)bx*8192 + (size_t)(w16 + quad*4 + r)*128 + col] = acc[n][r];
    }
  }
  {
    f32x4 acc[4];
    mm_band<4>(Pm, VlT, w16, chh*64, l16, quad, acc);
#pragma unroll
    for (int n = 0; n < 4; ++n) {
      int col = chh*64 + n*16 + l16;
#pragma unroll
      for (int r = 0; r < 4; ++r)
        obuf[(size_t)(t0 + w16 + quad*4 + r)*2048 + h*128 + col] = acc[n][r];
    }
  }
}

// ---------------- MFMA sequential recurrence (round-5 structure) ----------------
__global__ __launch_bounds__(256) void k_seq(const bf16* __restrict__ EF,
    const float* __restrict__ dSl, float* __restrict__ osb) {
  const int h = blockIdx.x >> 2, dq = blockIdx.x & 3;
  const int tid = threadIdx.x, wave = tid >> 6, lane = tid & 63;
  const int l16 = lane & 15, quad = lane >> 4;
  const int mb = wave * 16;
  __shared__ bf16 ebuf[2][13824];
  __shared__ bf16 Sthi[32*S72], Stlo[32*S72];
  for (int i = tid; i < 2304; i += 256) { Sthi[i] = (bf16)0.f; Stlo[i] = (bf16)0.f; }
  {
    const bf16* efg = EF + (size_t)h * 13824;
    for (int i = tid; i < 1728; i += 256)
      __builtin_amdgcn_global_load_lds(
        (__attribute__((address_space(1))) void*)(efg + i*8),
        (__attribute__((address_space(3))) void*)(&ebuf[0][i*8]), 16, 0, 0);
  }
  float dsv[8];
  {
    size_t base = (size_t)h*8192 + dq*32;
#pragma unroll
    for (int nt = 0; nt < 2; ++nt)
#pragma unroll
      for (int r = 0; r < 4; ++r)
        dsv[nt*4+r] = dSl[base + (size_t)(mb + quad*4 + r)*128 + nt*16 + l16];
  }
  __syncthreads();
#pragma unroll 1
  for (int c = 0; c < 32; ++c) {
    const int cur = c & 1, nxt = cur ^ 1;
    float dsn[8] = {};
    if (c + 1 < 32) {
      const bf16* efg = EF + (size_t)((c+1)*16 + h) * 13824;
      for (int i = tid; i < 1728; i += 256)
        __builtin_amdgcn_global_load_lds(
          (__attribute__((address_space(1))) void*)(efg + i*8),
          (__attribute__((address_space(3))) void*)(&ebuf[nxt][i*8]), 16, 0, 0);
      size_t base = (size_t)((c+1)*16 + h)*8192 + dq*32;
#pragma unroll
      for (int nt = 0; nt < 2; ++nt)
#pragma unroll
        for (int r = 0; r < 4; ++r)
          dsn[nt*4+r] = dSl[base + (size_t)(mb + quad*4 + r)*128 + nt*16 + l16];
    }
    const bf16* Eh = &ebuf[cur][0];
    const bf16* El = &ebuf[cur][4608];
    const bf16* Ff = &ebuf[cur][9216];
    bf16x8 bh[2][2], bl[2][2];
#pragma unroll
    for (int nt = 0; nt < 2; ++nt)
#pragma unroll
      for (int kt = 0; kt < 2; ++kt) {
        bh[nt][kt] = *(const bf16x8*)(Sthi + (nt*16 + l16)*S72 + kt*32 + quad*8);
        bl[nt][kt] = *(const bf16x8*)(Stlo + (nt*16 + l16)*S72 + kt*32 + quad*8);
      }
    f32x4 accS[2], accO[2];
#pragma unroll
    for (int nt = 0; nt < 2; ++nt) {
#pragma unroll
      for (int r = 0; r < 4; ++r) accS[nt][r] = dsv[nt*4+r];
      accO[nt][0]=0.f; accO[nt][1]=0.f; accO[nt][2]=0.f; accO[nt][3]=0.f;
    }
#pragma unroll
    for (int kt = 0; kt < 2; ++kt) {
      bf16x8 aeh = *(const bf16x8*)(Eh + (mb + l16)*S72 + kt*32 + quad*8);
      bf16x8 ael = *(const bf16x8*)(El + (mb + l16)*S72 + kt*32 + quad*8);
      bf16x8 aff = *(const bf16x8*)(Ff + (mb + l16)*S72 + kt*32 + quad*8);
#pragma unroll
      for (int nt = 0; nt < 2; ++nt) {
        accS[nt] = __builtin_amdgcn_mfma_f32_16x16x32_bf16(aeh, bh[nt][kt], accS[nt], 0, 0, 0);
        accS[nt] = __builtin_amdgcn_mfma_f32_16x16x32_bf16(aeh, bl[nt][kt], accS[nt], 0, 0, 0);
        accS[nt] = __builtin_amdgcn_mfma_f32_16x16x32_bf16(ael, bh[nt][kt], accS[nt], 0, 0, 0);
        accO[nt] = __builtin_amdgcn_mfma_f32_16x16x32_bf16(aff, bh[nt][kt], accO[nt], 0, 0, 0);
        accO[nt] = __builtin_amdgcn_mfma_f32_16x16x32_bf16(aff, bl[nt][kt], accO[nt], 0, 0, 0);
      }
    }
    __syncthreads();
    {
      int t0 = c*64;
#pragma unroll
      for (int nt = 0; nt < 2; ++nt)
#pragma unroll
        for (int r = 0; r < 4; ++r)
          osb[(size_t)(t0 + mb + quad*4 + r)*2048 + h*128 + dq*32 + nt*16 + l16] = accO[nt][r];
    }
#pragma unroll
    for (int nt = 0; nt < 2; ++nt) {
      bf16x4v hv, lv;
#pragma unroll
      for (int r = 0; r < 4; ++r) {
        float v = accS[nt][r];
        bf16 hb = (bf16)v;
        hv[r] = hb;
        lv[r] = (bf16)(v - (float)hb);
      }
      *(bf16x4v*)(Sthi + (nt*16 + l16)*S72 + mb + quad*4) = hv;
      *(bf16x4v*)(Stlo + (nt*16 + l16)*S72 + mb + quad*4) = lv;
    }
#pragma unroll
    for (int i = 0; i < 8; ++i) dsv[i] = dsn[i];
    __syncthreads();
  }
}

// ---------------- gated RMSNorm on o = O_loc + O_s, write bf16 ----------------
__global__ __launch_bounds__(64) void k_gatenorm(const float* __restrict__ o,
    const float* __restrict__ os, const bf16* __restrict__ gpre,
    const float* __restrict__ onw, bf16* __restrict__ og) {
  int t = blockIdx.x, hh = blockIdx.y, lane = threadIdx.x;
  size_t base = (size_t)t*2048 + hh*128 + lane*2;
  float2 o2 = *(const float2*)(o + base);
  float2 s2 = *(const float2*)(os + base);
  o2.x += s2.x; o2.y += s2.y;
  float ss = wredsum(o2.x*o2.x + o2.y*o2.y);
  float rs = rsqrtf(ss * (1.f/128.f) + 1e-5f);
  float2 nw = *(const float2*)(onw + lane*2);
  bf16x2v g2 = *(const bf16x2v*)(gpre + base);
  float g0 = (float)g2[0], g1 = (float)g2[1];
  float r0 = o2.x * rs * nw.x * (g0 * sigmoidf_(g0));
  float r1 = o2.y * rs * nw.y * (g1 * sigmoidf_(g1));
  bf16x2v b; b[0] = (bf16)r0; b[1] = (bf16)r1;
  *(bf16x2v*)(og + base) = b;
}

extern "C" void kernel_launch(void* const* d_in, const int* in_sizes, int n_in,
                              void* d_out, int out_size, void* d_ws, size_t ws_size,
                              hipStream_t stream) {
  const float* hs   = (const float*)d_in[0];
  const float* nw   = (const float*)d_in[1];
  const float* qw   = (const float*)d_in[2];
  const float* kw   = (const float*)d_in[3];
  const float* vw   = (const float*)d_in[4];
  const float* aw   = (const float*)d_in[5];
  const float* bw   = (const float*)d_in[6];
  const float* gw   = (const float*)d_in[7];
  const float* dtb  = (const float*)d_in[8];
  const float* alog = (const float*)d_in[9];
  const float* cqw  = (const float*)d_in[10];
  const float* ckw  = (const float*)d_in[11];
  const float* cvw  = (const float*)d_in[12];
  const float* onw  = (const float*)d_in[13];
  const float* opw  = (const float*)d_in[14];
  const float* ow   = (const float*)d_in[15];
  float* out = (float*)d_out;

  char* p = (char*)d_ws;
  auto alloc = [&](size_t bytes) { char* r = p; p += (bytes + 255) & ~255ull; return r; };
  bf16*  xb    = (bf16*) alloc((size_t)2048*1024*2);   // } dSl aliases xb..gwb (16 MB,
  bf16*  qwb   = (bf16*) alloc((size_t)1024*1024*2);   // } all dead after k_gemm_proj)
  bf16*  kwb   = (bf16*) alloc((size_t)1024*1024*2);
  bf16*  vwb   = (bf16*) alloc((size_t)2048*1024*2);
  bf16*  gwb   = (bf16*) alloc((size_t)2048*1024*2);
  bf16*  opwb  = (bf16*) alloc((size_t)1024*2048*2);
  bf16*  owb   = (bf16*) alloc((size_t)1024*1024*2);
  bf16*  qpre  = (bf16*) alloc((size_t)2048*1024*2);
  bf16*  kpre  = (bf16*) alloc((size_t)2048*1024*2);
  bf16*  vpre  = (bf16*) alloc((size_t)2048*2048*2);
  bf16*  gpre  = (bf16*) alloc((size_t)2048*2048*2);
  float* graw  = (float*)alloc((size_t)2048*16*4);
  float* btb   = (float*)alloc((size_t)2048*16*4);
  float* ob    = (float*)alloc((size_t)2048*2048*4);
  bf16*  ogb   = (bf16*) alloc((size_t)2048*2048*2);
  bf16*  h1b   = (bf16*) alloc((size_t)2048*1024*2);
  bf16*  EF    = (bf16*) alloc((size_t)512*13824*2);
  float* osb   = (float*)alloc((size_t)512*8192*4);
  float* dSl   = (float*)xb;   // 16 MB over xb..gwb (dead after k_gemm_proj)

  k_pre<<<2048+4608, 256, 0, stream>>>(hs, nw, aw, bw, dtb, alog, xb, graw, btb,
                                       qw, kw, vw, gw, opw, ow,
                                       qwb, kwb, vwb, gwb, opwb, owb);
  k_gemm_proj<<<dim3(48,16,1), 256, 0, stream>>>(xb, qwb, kwb, vwb, gwb, qpre, kpre, vpre, gpre);
  k_prepass<<<512, 512, 0, stream>>>(qpre, kpre, vpre, cqw, ckw, cvw, graw, btb, EF, dSl, ob);
  k_seq<<<64, 256, 0, stream>>>(EF, dSl, osb);
  k_gatenorm<<<dim3(2048,16,1), 64, 0, stream>>>(ob, osb, gpre, onw, ogb);
  k_gemm_bt64<bf16><<<dim3(16,16,1), 256, 0, stream>>>(ogb, opwb, h1b, 1024, 2048);
  k_gemm_bt64<float><<<dim3(16,16,1), 256, 0, stream>>>(h1b, owb, out, 1024, 1024);
}